// Round 4
// baseline (1905.516 us; speedup 1.0000x reference)
//
#include <hip/hip_runtime.h>
#include <hip/hip_bf16.h>

#define N_NODES 100000
#define N_EDGES 640000
#define DD 128
#define DE 32

typedef __attribute__((ext_vector_type(8))) short bf8v;
typedef __attribute__((ext_vector_type(4))) float f4v;

__device__ __forceinline__ float gelu_f(float x) {
    return 0.5f * x * (1.0f + erff(x * 0.70710678118654752f));
}
// tanh-form gelu (max abs dev from exact ~1e-3) — used only in edge hot loop
__device__ __forceinline__ float gelu_t(float x) {
    float y = 0.7978845608f * (x + 0.044715f * x * x * x);
    float t = __expf(-2.0f * fabsf(y));
    float th = (1.0f - t) / (1.0f + t);
    th = copysignf(th, y);
    return 0.5f * x * (1.0f + th);
}
__device__ __forceinline__ float bf2f(ushort u) {
    union { uint u; float f; } t; t.u = ((uint)u) << 16; return t.f;
}
__device__ __forceinline__ ushort f2bf(float f) {
    union { float f; uint u; } t; t.f = f;
    uint r = (t.u + 0x7fffu + ((t.u >> 16) & 1u)) >> 16;
    return (ushort)r;
}

// ---------------- CSR build ----------------
__global__ void k_count(const int* __restrict__ ei, int* __restrict__ cnt) {
    int e = blockIdx.x * blockDim.x + threadIdx.x;
    if (e < N_EDGES) atomicAdd(&cnt[ei[N_EDGES + e]], 1);
}

__global__ void k_scan(const int* __restrict__ cnt, int* __restrict__ rowstart) {
    __shared__ int part[1024];
    int t = threadIdx.x;
    const int chunk = (N_NODES + 1023) / 1024;
    int lo = t * chunk, hi = min(lo + chunk, N_NODES);
    int s = 0;
    for (int i = lo; i < hi; i++) s += cnt[i];
    part[t] = s;
    __syncthreads();
    for (int off = 1; off < 1024; off <<= 1) {
        int v = (t >= off) ? part[t - off] : 0;
        __syncthreads();
        part[t] += v;
        __syncthreads();
    }
    int run = (t == 0) ? 0 : part[t - 1];
    for (int i = lo; i < hi; i++) { rowstart[i] = run; run += cnt[i]; }
    if (lo < N_NODES && hi == N_NODES) rowstart[N_NODES] = run;
}

__global__ void k_cursor(const int* __restrict__ rowstart, int* __restrict__ cursor) {
    int n = blockIdx.x * blockDim.x + threadIdx.x;
    if (n < N_NODES) cursor[n] = rowstart[n];
}

// writes both permuted edge id and src node id
__global__ void k_scatter(const int* __restrict__ ei, int* __restrict__ cursor,
                          int* __restrict__ eord, int* __restrict__ esrc) {
    int e = blockIdx.x * blockDim.x + threadIdx.x;
    if (e < N_EDGES) {
        int pos = atomicAdd(&cursor[ei[N_EDGES + e]], 1);
        eord[pos] = e;
        esrc[pos] = ei[e];
    }
}

__global__ void k_degflag(const int* __restrict__ rowstart, float* __restrict__ flag) {
    int n = blockIdx.x * blockDim.x + threadIdx.x;
    if (n < N_NODES) flag[n] = (rowstart[n + 1] > rowstart[n]) ? 1.0f : 0.0f;
}

// ---------------- composite edge weights (fp32) ----------------
__global__ void k_prep(const float* __restrict__ edge_w, const float* __restrict__ edge_b,
                       const float* __restrict__ msg_w1, const float* __restrict__ msg_b1,
                       float* __restrict__ We1, float* __restrict__ bc) {
    int j = threadIdx.x;
    int c = blockIdx.x;
    int l = blockIdx.y;
    const float* w1 = msg_w1 + (size_t)l * DD * DD;
    if (c < DE) {
        float s = 0.0f;
        for (int k = 0; k < DD; k++) s += edge_w[c*DD + k] * w1[k*DD + j];
        We1[((size_t)l*DE + c)*DD + j] = s;
    } else {
        float s = msg_b1[l*DD + j];
        for (int k = 0; k < DD; k++) s += edge_b[k] * w1[k*DD + j];
        bc[l*DD + j] = s;
    }
}

// transpose fp32 [R][C] -> bf16 [C][R]
__global__ void k_tbf(const float* __restrict__ in, ushort* __restrict__ out, int R, int C) {
    int idx = blockIdx.x * 256 + threadIdx.x;
    if (idx < R * C) {
        int r = idx / C, c = idx % C;
        out[(size_t)c * R + r] = f2bf(in[idx]);
    }
}

// ---------------- no-LDS wave-tile GEMM: out[M,128] = A[M,128] @ Wt^T ----------------
// Each wave: 16 rows x 128 cols. A-frags + B-frags straight from global (B is L2-hot).
enum { EPI_EMB = 0, EPI_BF16 = 1 };

template<int EPI, int AFP32>
__global__ __launch_bounds__(256) void k_gemm(
    const void* __restrict__ Av,
    const ushort* __restrict__ Wt,          // [128 out][128 k] bf16
    const float* __restrict__ bias,
    ushort* __restrict__ outb, float* __restrict__ outf, int M)
{
    int tid = threadIdx.x;
    int lane = tid & 63, w = tid >> 6;
    int base = (blockIdx.x * 4 + w) * 16;
    if (base >= M) return;
    int cq = lane & 15, quad = lane >> 4;
    bf8v a[4];
    if (AFP32) {
        const float* Af = (const float*)Av + (size_t)(base + cq) * DD;
#pragma unroll
        for (int kc = 0; kc < 4; kc++) {
            float4 v0 = *(const float4*)(Af + kc * 32 + quad * 8);
            float4 v1 = *(const float4*)(Af + kc * 32 + quad * 8 + 4);
            bf8v t;
            t[0] = (short)f2bf(v0.x); t[1] = (short)f2bf(v0.y);
            t[2] = (short)f2bf(v0.z); t[3] = (short)f2bf(v0.w);
            t[4] = (short)f2bf(v1.x); t[5] = (short)f2bf(v1.y);
            t[6] = (short)f2bf(v1.z); t[7] = (short)f2bf(v1.w);
            a[kc] = t;
        }
    } else {
        const ushort* Ab = (const ushort*)Av + (size_t)(base + cq) * DD;
#pragma unroll
        for (int kc = 0; kc < 4; kc++)
            a[kc] = *(const bf8v*)(Ab + kc * 32 + quad * 8);
    }
    f4v acc[8];
#pragma unroll
    for (int ct = 0; ct < 8; ct++) acc[ct] = 0.0f;
#pragma unroll
    for (int ct = 0; ct < 8; ct++) {
        const ushort* Wr = Wt + (size_t)(ct * 16 + cq) * DD;
#pragma unroll
        for (int kc = 0; kc < 4; kc++) {
            bf8v b = *(const bf8v*)(Wr + kc * 32 + quad * 8);
            acc[ct] = __builtin_amdgcn_mfma_f32_16x16x32_bf16(a[kc], b, acc[ct], 0, 0, 0);
        }
    }
    int r0 = base + quad * 4;
#pragma unroll
    for (int ct = 0; ct < 8; ct++) {
        int col = ct * 16 + cq;
        float b_ = bias ? bias[col] : 0.0f;
#pragma unroll
        for (int i = 0; i < 4; i++) {
            float v = acc[ct][i] + b_;
            if (EPI == EPI_EMB) outf[(size_t)(r0 + i) * DD + col] = v;
            else                outb[(size_t)(r0 + i) * DD + col] = f2bf(v);
        }
    }
}

// ---------------- fused c+d: B1 = agg@w2 + flag*b2 ; T = gelu(B1@u1 + bu1) ----------------
__global__ __launch_bounds__(256) void k_cd(
    const ushort* __restrict__ agg,
    const ushort* __restrict__ w2T, const float* __restrict__ b2,
    const float* __restrict__ flag,
    const ushort* __restrict__ u1T, const float* __restrict__ bu1,
    ushort* __restrict__ T, int M)
{
    __shared__ ushort tr[4][16 * 136];
    int tid = threadIdx.x;
    int lane = tid & 63, w = tid >> 6;
    int base = (blockIdx.x * 4 + w) * 16;
    int cq = lane & 15, quad = lane >> 4;
    f4v acc[8];
    if (base < M) {
        bf8v a[4];
        const ushort* Ab = agg + (size_t)(base + cq) * DD;
#pragma unroll
        for (int kc = 0; kc < 4; kc++)
            a[kc] = *(const bf8v*)(Ab + kc * 32 + quad * 8);
#pragma unroll
        for (int ct = 0; ct < 8; ct++) acc[ct] = 0.0f;
#pragma unroll
        for (int ct = 0; ct < 8; ct++) {
            const ushort* Wr = w2T + (size_t)(ct * 16 + cq) * DD;
#pragma unroll
            for (int kc = 0; kc < 4; kc++) {
                bf8v b = *(const bf8v*)(Wr + kc * 32 + quad * 8);
                acc[ct] = __builtin_amdgcn_mfma_f32_16x16x32_bf16(a[kc], b, acc[ct], 0, 0, 0);
            }
        }
        int r0 = base + quad * 4;
        float fl[4];
#pragma unroll
        for (int i = 0; i < 4; i++) fl[i] = flag[r0 + i];
#pragma unroll
        for (int ct = 0; ct < 8; ct++) {
            int col = ct * 16 + cq;
            float b_ = b2[col];
#pragma unroll
            for (int i = 0; i < 4; i++)
                tr[w][(quad * 4 + i) * 136 + col] = f2bf(acc[ct][i] + fl[i] * b_);
        }
    }
    __syncthreads();
    if (base >= M) return;
    bf8v a2[4];
#pragma unroll
    for (int kc = 0; kc < 4; kc++)
        a2[kc] = *(const bf8v*)(&tr[w][cq * 136 + kc * 32 + quad * 8]);
    int r0 = base + quad * 4;
#pragma unroll
    for (int h = 0; h < 2; h++) {
#pragma unroll
        for (int ct = 0; ct < 8; ct++) acc[ct] = 0.0f;
#pragma unroll
        for (int ct = 0; ct < 8; ct++) {
            const ushort* Wr = u1T + (size_t)(h * 128 + ct * 16 + cq) * DD;
#pragma unroll
            for (int kc = 0; kc < 4; kc++) {
                bf8v b = *(const bf8v*)(Wr + kc * 32 + quad * 8);
                acc[ct] = __builtin_amdgcn_mfma_f32_16x16x32_bf16(a2[kc], b, acc[ct], 0, 0, 0);
            }
        }
#pragma unroll
        for (int ct = 0; ct < 8; ct++) {
            int col = ct * 16 + cq;
            float b_ = bu1[h * 128 + col];
#pragma unroll
            for (int i = 0; i < 4; i++)
                T[(size_t)(r0 + i) * 256 + h * 128 + col] = f2bf(gelu_f(acc[ct][i] + b_));
        }
    }
}

// ---------------- fused e+f: u = T@u2 + bu2 ; node = LN(node + u) ----------------
__global__ __launch_bounds__(256) void k_ef(
    const ushort* __restrict__ T,
    const ushort* __restrict__ u2T, const float* __restrict__ bu2,
    float* __restrict__ node,
    const float* __restrict__ lg, const float* __restrict__ lb, int M)
{
    int tid = threadIdx.x;
    int lane = tid & 63, w = tid >> 6;
    int base = (blockIdx.x * 4 + w) * 16;
    if (base >= M) return;
    int cq = lane & 15, quad = lane >> 4;
    f4v acc[8];
#pragma unroll
    for (int ct = 0; ct < 8; ct++) acc[ct] = 0.0f;
#pragma unroll
    for (int kh = 0; kh < 2; kh++) {
        bf8v a[4];
        const ushort* Ab = T + (size_t)(base + cq) * 256 + kh * 128;
#pragma unroll
        for (int kc = 0; kc < 4; kc++)
            a[kc] = *(const bf8v*)(Ab + kc * 32 + quad * 8);
#pragma unroll
        for (int ct = 0; ct < 8; ct++) {
            const ushort* Wr = u2T + (size_t)(ct * 16 + cq) * 256 + kh * 128;
#pragma unroll
            for (int kc = 0; kc < 4; kc++) {
                bf8v b = *(const bf8v*)(Wr + kc * 32 + quad * 8);
                acc[ct] = __builtin_amdgcn_mfma_f32_16x16x32_bf16(a[kc], b, acc[ct], 0, 0, 0);
            }
        }
    }
    int r0 = base + quad * 4;
    float x[8][4], lgc[8], lbc[8];
#pragma unroll
    for (int ct = 0; ct < 8; ct++) {
        int col = ct * 16 + cq;
        float b_ = bu2[col];
        lgc[ct] = lg[col]; lbc[ct] = lb[col];
#pragma unroll
        for (int i = 0; i < 4; i++)
            x[ct][i] = acc[ct][i] + b_ + node[(size_t)(r0 + i) * DD + col];
    }
#pragma unroll
    for (int i = 0; i < 4; i++) {
        float s = 0.0f;
#pragma unroll
        for (int ct = 0; ct < 8; ct++) s += x[ct][i];
        s += __shfl_xor(s, 1); s += __shfl_xor(s, 2);
        s += __shfl_xor(s, 4); s += __shfl_xor(s, 8);
        float m = s * (1.0f / 128.0f);
        float vv = 0.0f;
#pragma unroll
        for (int ct = 0; ct < 8; ct++) { float d = x[ct][i] - m; vv += d * d; }
        vv += __shfl_xor(vv, 1); vv += __shfl_xor(vv, 2);
        vv += __shfl_xor(vv, 4); vv += __shfl_xor(vv, 8);
        float inv = rsqrtf(vv * (1.0f / 128.0f) + 1e-5f);
#pragma unroll
        for (int ct = 0; ct < 8; ct++) {
            int col = ct * 16 + cq;
            node[(size_t)(r0 + i) * DD + col] = (x[ct][i] - m) * inv * lgc[ct] + lbc[ct];
        }
    }
}

// ---------------- edge aggregation: 2 waves per node, 1 col per lane ----------------
__global__ __launch_bounds__(256) void k_edge(
    const ushort* __restrict__ nodeW1, const float* __restrict__ edge_attr,
    const int* __restrict__ esrc, const int* __restrict__ eord,
    const int* __restrict__ rowstart,
    const float* __restrict__ We1, const float* __restrict__ bc,
    ushort* __restrict__ aggh)
{
    int lane = threadIdx.x & 63;
    int w = threadIdx.x >> 6;
    int n = blockIdx.x * 2 + (w >> 1);
    int col = (w & 1) * 64 + lane;
    float wv[DE];
#pragma unroll
    for (int c = 0; c < DE; c++) wv[c] = We1[c * DD + col];
    float bcv = bc[col];
    int rs = rowstart[n], re = rowstart[n + 1];
    float acc = 0.0f;
    int j = rs;
    for (; j + 1 < re; j += 2) {
        int e0 = __builtin_amdgcn_readfirstlane(eord[j]);
        int e1 = __builtin_amdgcn_readfirstlane(eord[j + 1]);
        int s0 = __builtin_amdgcn_readfirstlane(esrc[j]);
        int s1 = __builtin_amdgcn_readfirstlane(esrc[j + 1]);
        float nv0 = bf2f(nodeW1[(size_t)s0 * DD + col]);
        float nv1 = bf2f(nodeW1[(size_t)s1 * DD + col]);
        const float* ea0 = edge_attr + (size_t)e0 * DE;
        const float* ea1 = edge_attr + (size_t)e1 * DE;
        float v0 = bcv + nv0, v1 = bcv + nv1;
#pragma unroll
        for (int c = 0; c < DE; c++) {
            v0 += ea0[c] * wv[c];
            v1 += ea1[c] * wv[c];
        }
        acc += gelu_t(v0) + gelu_t(v1);
    }
    if (j < re) {
        int e0 = __builtin_amdgcn_readfirstlane(eord[j]);
        int s0 = __builtin_amdgcn_readfirstlane(esrc[j]);
        float v0 = bcv + bf2f(nodeW1[(size_t)s0 * DD + col]);
        const float* ea0 = edge_attr + (size_t)e0 * DE;
#pragma unroll
        for (int c = 0; c < DE; c++) v0 += ea0[c] * wv[c];
        acc += gelu_t(v0);
    }
    int deg = re - rs;
    float inv = (deg > 0) ? 1.0f / (float)deg : 0.0f;
    aggh[(size_t)n * DD + col] = f2bf(acc * inv);
}

// ---------------- pooling (fp32 node master) ----------------
__global__ void k_pool_partial(const float* __restrict__ node, float* __restrict__ partial) {
    int seg = blockIdx.x, chunk = blockIdx.y, j = threadIdx.x;
    int segbase = seg * 14286;
    int segcnt = (seg == 6) ? 14284 : 14286;
    int per = (segcnt + 15) / 16;
    int lo = chunk * per, hi = min(lo + per, segcnt);
    float s = 0.0f;
    for (int r = lo; r < hi; r++) s += node[(size_t)(segbase + r) * DD + j];
    partial[(seg * 16 + chunk) * DD + j] = s;
}

__global__ void k_pool_final(const float* __restrict__ partial, const float* __restrict__ g,
                             const float* __restrict__ b, float* __restrict__ out) {
    __shared__ float red[128];
    int j = threadIdx.x;
    float tok[8];
    float tot = 0.0f;
#pragma unroll
    for (int s = 0; s < 7; s++) {
        float v = 0.0f;
        for (int c = 0; c < 16; c++) v += partial[(s * 16 + c) * DD + j];
        tok[1 + s] = v / ((s == 6) ? 14284.0f : 14286.0f);
        tot += v;
    }
    tok[0] = tot / 100000.0f;
    for (int t = 0; t < 8; t++) {
        float x = tok[t];
        red[j] = x; __syncthreads();
        for (int off = 64; off > 0; off >>= 1) {
            if (j < off) red[j] += red[j + off];
            __syncthreads();
        }
        float m = red[0] / 128.0f;
        __syncthreads();
        float d = x - m;
        red[j] = d * d; __syncthreads();
        for (int off = 64; off > 0; off >>= 1) {
            if (j < off) red[j] += red[j + off];
            __syncthreads();
        }
        float var = red[0] / 128.0f;
        __syncthreads();
        out[t * DD + j] = d * rsqrtf(var + 1e-5f) * g[j] + b[j];
    }
}

extern "C" void kernel_launch(void* const* d_in, const int* in_sizes, int n_in,
                              void* d_out, int out_size, void* d_ws, size_t ws_size,
                              hipStream_t stream) {
    const float* x         = (const float*)d_in[0];
    const int*   ei        = (const int*)d_in[1];
    const float* edge_attr = (const float*)d_in[2];
    const float* node_w    = (const float*)d_in[3];
    const float* node_b    = (const float*)d_in[4];
    const float* edge_w    = (const float*)d_in[5];
    const float* edge_b    = (const float*)d_in[6];
    const float* msg_w1    = (const float*)d_in[7];
    const float* msg_b1    = (const float*)d_in[8];
    const float* msg_w2    = (const float*)d_in[9];
    const float* msg_b2    = (const float*)d_in[10];
    const float* upd_w1    = (const float*)d_in[11];
    const float* upd_b1    = (const float*)d_in[12];
    const float* upd_w2    = (const float*)d_in[13];
    const float* upd_b2    = (const float*)d_in[14];
    const float* ln_g      = (const float*)d_in[15];
    const float* ln_b      = (const float*)d_in[16];
    const float* out_g     = (const float*)d_in[17];
    const float* out_b     = (const float*)d_in[18];
    float* out = (float*)d_out;

    // ---- workspace layout (~161 MB) ----
    float*  node_f  = (float*)d_ws;                              // N*128 fp32 master
    ushort* slotA   = (ushort*)(node_f + (size_t)N_NODES * DD);  // N*128 bf16 nodeW1
    ushort* aggb    = slotA + (size_t)N_NODES * DD;              // N*128 bf16 agg
    ushort* Tfull   = aggb + (size_t)N_NODES * DD;               // N*256 bf16 T
    float*  We1     = (float*)(Tfull + (size_t)N_NODES * 256);   // 3*32*128
    float*  bc      = We1 + 3 * DE * DD;                         // 3*128
    float*  partial = bc + 3 * DD;                               // 7*16*128
    float*  degflag = partial + 7 * 16 * DD;                     // N
    ushort* node_wT = (ushort*)(degflag + N_NODES);              // 128*128
    ushort* msg_w1T = node_wT + DD * DD;                         // 3*128*128
    ushort* msg_w2T = msg_w1T + 3 * DD * DD;                     // 3*128*128
    ushort* upd_w1T = msg_w2T + 3 * DD * DD;                     // 3*256*128
    ushort* upd_w2T = upd_w1T + 3 * 256 * DD;                    // 3*128*256
    int* cnt        = (int*)(upd_w2T + 3 * DD * 256);            // N
    int* rowstart   = cnt + N_NODES;                             // N+1
    int* cursor     = rowstart + N_NODES + 1;                    // N
    int* eord       = cursor + N_NODES;                          // E
    int* esrc       = eord + N_EDGES;                            // E

    hipMemsetAsync(cnt, 0, N_NODES * sizeof(int), stream);
    k_count  <<<(N_EDGES + 255) / 256, 256, 0, stream>>>(ei, cnt);
    k_scan   <<<1, 1024, 0, stream>>>(cnt, rowstart);
    k_cursor <<<(N_NODES + 255) / 256, 256, 0, stream>>>(rowstart, cursor);
    k_scatter<<<(N_EDGES + 255) / 256, 256, 0, stream>>>(ei, cursor, eord, esrc);
    k_degflag<<<(N_NODES + 255) / 256, 256, 0, stream>>>(rowstart, degflag);
    k_prep   <<<dim3(DE + 1, 3), DD, 0, stream>>>(edge_w, edge_b, msg_w1, msg_b1, We1, bc);

    // weight transposes -> bf16 [out][in]
    k_tbf<<<(DD*DD + 255)/256, 256, 0, stream>>>(node_w, node_wT, DD, DD);
    for (int l = 0; l < 3; l++) {
        k_tbf<<<(DD*DD + 255)/256, 256, 0, stream>>>(msg_w1 + (size_t)l*DD*DD, msg_w1T + (size_t)l*DD*DD, DD, DD);
        k_tbf<<<(DD*DD + 255)/256, 256, 0, stream>>>(msg_w2 + (size_t)l*DD*DD, msg_w2T + (size_t)l*DD*DD, DD, DD);
        k_tbf<<<(DD*256 + 255)/256, 256, 0, stream>>>(upd_w1 + (size_t)l*DD*256, upd_w1T + (size_t)l*256*DD, DD, 256);
        k_tbf<<<(256*DD + 255)/256, 256, 0, stream>>>(upd_w2 + (size_t)l*256*DD, upd_w2T + (size_t)l*DD*256, 256, DD);
    }

    const int GB = (N_NODES / 16 + 3) / 4;  // 1563 blocks of 4 waves
    // embed: node_f = x @ node_w + node_b
    k_gemm<EPI_EMB, 1><<<GB, 256, 0, stream>>>(x, node_wT, node_b, nullptr, node_f, N_NODES);

    for (int l = 0; l < 3; l++) {
        // a: nodeW1 = node @ msg_w1
        k_gemm<EPI_BF16, 1><<<GB, 256, 0, stream>>>(node_f, msg_w1T + (size_t)l*DD*DD,
            nullptr, slotA, nullptr, N_NODES);
        // b: edge aggregation
        k_edge<<<N_NODES / 2, 256, 0, stream>>>(slotA, edge_attr, esrc, eord, rowstart,
            We1 + (size_t)l*DE*DD, bc + (size_t)l*DD, aggb);
        // c+d: T = gelu((agg @ msg_w2 + flag*b2) @ upd_w1 + bu1)
        k_cd<<<GB, 256, 0, stream>>>(aggb, msg_w2T + (size_t)l*DD*DD, msg_b2 + (size_t)l*DD,
            degflag, upd_w1T + (size_t)l*256*DD, upd_b1 + (size_t)l*256, Tfull, N_NODES);
        // e+f: node = LN(node + T @ upd_w2 + bu2)
        k_ef<<<GB, 256, 0, stream>>>(Tfull, upd_w2T + (size_t)l*DD*256, upd_b2 + (size_t)l*DD,
            node_f, ln_g + (size_t)l*DD, ln_b + (size_t)l*DD, N_NODES);
    }

    k_pool_partial<<<dim3(7, 16), DD, 0, stream>>>(node_f, partial);
    k_pool_final  <<<1, DD, 0, stream>>>(partial, out_g, out_b, out);
}

// Round 5
// 1833.678 us; speedup vs baseline: 1.0392x; 1.0392x over previous
//
#include <hip/hip_runtime.h>
#include <hip/hip_bf16.h>

#define N_NODES 100000
#define N_EDGES 640000
#define DD 128
#define DE 32

typedef __attribute__((ext_vector_type(8))) short bf8v;
typedef __attribute__((ext_vector_type(4))) float f4v;

__device__ __forceinline__ float gelu_f(float x) {
    return 0.5f * x * (1.0f + erff(x * 0.70710678118654752f));
}
__device__ __forceinline__ float gelu_t(float x) {
    float y = 0.7978845608f * (x + 0.044715f * x * x * x);
    float t = __expf(-2.0f * fabsf(y));
    float th = (1.0f - t) / (1.0f + t);
    th = copysignf(th, y);
    return 0.5f * x * (1.0f + th);
}
__device__ __forceinline__ float bf2f(ushort u) {
    union { uint u; float f; } t; t.u = ((uint)u) << 16; return t.f;
}
__device__ __forceinline__ ushort f2bf(float f) {
    union { float f; uint u; } t; t.f = f;
    uint r = (t.u + 0x7fffu + ((t.u >> 16) & 1u)) >> 16;
    return (ushort)r;
}

// ---------------- CSR build ----------------
__global__ void k_count(const int* __restrict__ ei, int* __restrict__ cnt) {
    int e = blockIdx.x * blockDim.x + threadIdx.x;
    if (e < N_EDGES) atomicAdd(&cnt[ei[N_EDGES + e]], 1);
}

__global__ void k_scan(const int* __restrict__ cnt, int* __restrict__ rowstart) {
    __shared__ int part[1024];
    int t = threadIdx.x;
    const int chunk = (N_NODES + 1023) / 1024;
    int lo = t * chunk, hi = min(lo + chunk, N_NODES);
    int s = 0;
    for (int i = lo; i < hi; i++) s += cnt[i];
    part[t] = s;
    __syncthreads();
    for (int off = 1; off < 1024; off <<= 1) {
        int v = (t >= off) ? part[t - off] : 0;
        __syncthreads();
        part[t] += v;
        __syncthreads();
    }
    int run = (t == 0) ? 0 : part[t - 1];
    for (int i = lo; i < hi; i++) { rowstart[i] = run; run += cnt[i]; }
    if (lo < N_NODES && hi == N_NODES) rowstart[N_NODES] = run;
}

__global__ void k_cursor(const int* __restrict__ rowstart, int* __restrict__ cursor) {
    int n = blockIdx.x * blockDim.x + threadIdx.x;
    if (n < N_NODES) cursor[n] = rowstart[n];
}

__global__ void k_scatter(const int* __restrict__ ei, int* __restrict__ cursor,
                          int* __restrict__ eord, int* __restrict__ esrc) {
    int e = blockIdx.x * blockDim.x + threadIdx.x;
    if (e < N_EDGES) {
        int pos = atomicAdd(&cursor[ei[N_EDGES + e]], 1);
        eord[pos] = e;
        esrc[pos] = ei[e];
    }
}

__global__ void k_degflag(const int* __restrict__ rowstart, float* __restrict__ flag) {
    int n = blockIdx.x * blockDim.x + threadIdx.x;
    if (n < N_NODES) flag[n] = (rowstart[n + 1] > rowstart[n]) ? 1.0f : 0.0f;
}

// ---------------- composite edge weights (fp32) ----------------
__global__ void k_prep(const float* __restrict__ edge_w, const float* __restrict__ edge_b,
                       const float* __restrict__ msg_w1, const float* __restrict__ msg_b1,
                       float* __restrict__ We1, float* __restrict__ bc) {
    int j = threadIdx.x;
    int c = blockIdx.x;
    int l = blockIdx.y;
    const float* w1 = msg_w1 + (size_t)l * DD * DD;
    if (c < DE) {
        float s = 0.0f;
        for (int k = 0; k < DD; k++) s += edge_w[c*DD + k] * w1[k*DD + j];
        We1[((size_t)l*DE + c)*DD + j] = s;
    } else {
        float s = msg_b1[l*DD + j];
        for (int k = 0; k < DD; k++) s += edge_b[k] * w1[k*DD + j];
        bc[l*DD + j] = s;
    }
}

// transpose fp32 [R][C] -> bf16 [C][R]
__global__ void k_tbf(const float* __restrict__ in, ushort* __restrict__ out, int R, int C) {
    int idx = blockIdx.x * 256 + threadIdx.x;
    if (idx < R * C) {
        int r = idx / C, c = idx % C;
        out[(size_t)c * R + r] = f2bf(in[idx]);
    }
}

// ---------------- embed + fused nodeW1(l=0) ----------------
__global__ __launch_bounds__(256) void k_embed(
    const float* __restrict__ x, const ushort* __restrict__ WT,
    const float* __restrict__ bias, const ushort* __restrict__ W1T,
    float* __restrict__ node, ushort* __restrict__ slotA, int M)
{
    __shared__ ushort tr[4][16 * 136];
    int tid = threadIdx.x, lane = tid & 63, w = tid >> 6;
    int base = (blockIdx.x * 4 + w) * 16;
    bool act = base < M;
    int cq = lane & 15, quad = lane >> 4;
    ushort* trw = tr[w];
    f4v acc[8];
    if (act) {
        bf8v a[4];
        const float* Af = x + (size_t)(base + cq) * DD;
#pragma unroll
        for (int kc = 0; kc < 4; kc++) {
            float4 v0 = *(const float4*)(Af + kc * 32 + quad * 8);
            float4 v1 = *(const float4*)(Af + kc * 32 + quad * 8 + 4);
            bf8v t;
            t[0]=(short)f2bf(v0.x); t[1]=(short)f2bf(v0.y); t[2]=(short)f2bf(v0.z); t[3]=(short)f2bf(v0.w);
            t[4]=(short)f2bf(v1.x); t[5]=(short)f2bf(v1.y); t[6]=(short)f2bf(v1.z); t[7]=(short)f2bf(v1.w);
            a[kc] = t;
        }
#pragma unroll
        for (int ct = 0; ct < 8; ct++) acc[ct] = 0.0f;
#pragma unroll
        for (int ct = 0; ct < 8; ct++) {
            const ushort* Wr = WT + (size_t)(ct * 16 + cq) * DD;
#pragma unroll
            for (int kc = 0; kc < 4; kc++)
                acc[ct] = __builtin_amdgcn_mfma_f32_16x16x32_bf16(a[kc],
                    *(const bf8v*)(Wr + kc * 32 + quad * 8), acc[ct], 0, 0, 0);
        }
        int r0 = base + quad * 4;
#pragma unroll
        for (int ct = 0; ct < 8; ct++) {
            int col = ct * 16 + cq;
            float b_ = bias[col];
#pragma unroll
            for (int i = 0; i < 4; i++) {
                float v = acc[ct][i] + b_;
                node[(size_t)(r0 + i) * DD + col] = v;
                trw[(quad * 4 + i) * 136 + col] = f2bf(v);
            }
        }
    }
    __syncthreads();
    if (act) {
        bf8v a2[4];
#pragma unroll
        for (int kc = 0; kc < 4; kc++)
            a2[kc] = *(const bf8v*)(trw + cq * 136 + kc * 32 + quad * 8);
#pragma unroll
        for (int ct = 0; ct < 8; ct++) acc[ct] = 0.0f;
#pragma unroll
        for (int ct = 0; ct < 8; ct++) {
            const ushort* Wr = W1T + (size_t)(ct * 16 + cq) * DD;
#pragma unroll
            for (int kc = 0; kc < 4; kc++)
                acc[ct] = __builtin_amdgcn_mfma_f32_16x16x32_bf16(a2[kc],
                    *(const bf8v*)(Wr + kc * 32 + quad * 8), acc[ct], 0, 0, 0);
        }
        int r0 = base + quad * 4;
#pragma unroll
        for (int ct = 0; ct < 8; ct++) {
            int col = ct * 16 + cq;
#pragma unroll
            for (int i = 0; i < 4; i++)
                slotA[(size_t)(r0 + i) * DD + col] = f2bf(acc[ct][i]);
        }
    }
}

// ---------------- per-edge embedding MLP (MFMA, K=32), CSR order, node-range pass ----------------
__global__ __launch_bounds__(256) void k_emb1(
    const int* __restrict__ eord, const float* __restrict__ edge_attr,
    const ushort* __restrict__ WeT, const float* __restrict__ bcv,
    const int* __restrict__ rowstart, int n_lo, int n_hi, int cap,
    ushort* __restrict__ emb1h)
{
    __shared__ ushort tr[4][16 * 136];
    int tid = threadIdx.x, lane = tid & 63, w = tid >> 6;
    int tbase = (blockIdx.x * 4 + w) * 16;
    int cq = lane & 15, quad = lane >> 4;
    int j_lo = rowstart[n_lo], j_hi = rowstart[n_hi];
    int cnt = j_hi - j_lo; if (cnt > cap) cnt = cap;
    ushort* trw = tr[w];
    bool act = tbase < cnt;
    if (act) {
        int jl = tbase + cq;
        bf8v a;
#pragma unroll
        for (int t = 0; t < 8; t++) a[t] = 0;
        if (jl < cnt) {
            int e = eord[j_lo + jl];
            const float* ea = edge_attr + (size_t)e * DE + quad * 8;
            float4 v0 = *(const float4*)(ea);
            float4 v1 = *(const float4*)(ea + 4);
            a[0]=(short)f2bf(v0.x); a[1]=(short)f2bf(v0.y); a[2]=(short)f2bf(v0.z); a[3]=(short)f2bf(v0.w);
            a[4]=(short)f2bf(v1.x); a[5]=(short)f2bf(v1.y); a[6]=(short)f2bf(v1.z); a[7]=(short)f2bf(v1.w);
        }
#pragma unroll
        for (int ct = 0; ct < 8; ct++) {
            bf8v b = *(const bf8v*)(WeT + (size_t)(ct * 16 + cq) * DE + quad * 8);
            f4v z; z = 0.0f;
            f4v r = __builtin_amdgcn_mfma_f32_16x16x32_bf16(a, b, z, 0, 0, 0);
            int col = ct * 16 + cq;
            float b_ = bcv[col];
#pragma unroll
            for (int i = 0; i < 4; i++)
                trw[(quad * 4 + i) * 136 + col] = f2bf(r[i] + b_);
        }
    }
    __syncthreads();
    if (act) {
        int r = lane >> 2, ch = (lane & 3) * 32;
        int jl = tbase + r;
        if (jl < cnt) {
#pragma unroll
            for (int q = 0; q < 4; q++) {
                bf8v v = *(const bf8v*)(trw + r * 136 + ch + q * 8);
                *(bf8v*)(emb1h + (size_t)jl * DD + ch + q * 8) = v;
            }
        }
    }
}

// ---------------- lean edge aggregation: gather + add + gelu + sum ----------------
__global__ __launch_bounds__(256) void k_edge(
    const ushort* __restrict__ emb1h, const ushort* __restrict__ nodeW1,
    const int* __restrict__ esrc, const int* __restrict__ rowstart,
    int n_lo, int n_hi, int cap, ushort* __restrict__ aggh)
{
    int lane = threadIdx.x & 63;
    int w = threadIdx.x >> 6;
    int n = n_lo + blockIdx.x * 2 + (w >> 1);
    if (n >= n_hi) return;
    int col = (w & 1) * 64 + lane;
    int j_lo = rowstart[n_lo];
    int rs = rowstart[n], re0 = rowstart[n + 1];
    int lim = j_lo + cap;
    int re = (re0 > lim) ? lim : re0;
    float acc = 0.0f;
    int j = rs;
    for (; j + 1 < re; j += 2) {
        int s0 = __builtin_amdgcn_readfirstlane(esrc[j]);
        int s1 = __builtin_amdgcn_readfirstlane(esrc[j + 1]);
        float e0 = bf2f(emb1h[(size_t)(j - j_lo) * DD + col]);
        float e1 = bf2f(emb1h[(size_t)(j + 1 - j_lo) * DD + col]);
        float nv0 = bf2f(nodeW1[(size_t)s0 * DD + col]);
        float nv1 = bf2f(nodeW1[(size_t)s1 * DD + col]);
        acc += gelu_t(e0 + nv0) + gelu_t(e1 + nv1);
    }
    if (j < re) {
        int s0 = __builtin_amdgcn_readfirstlane(esrc[j]);
        acc += gelu_t(bf2f(emb1h[(size_t)(j - j_lo) * DD + col])
                      + bf2f(nodeW1[(size_t)s0 * DD + col]));
    }
    int deg = re0 - rs;
    float inv = (deg > 0) ? 1.0f / (float)deg : 0.0f;
    aggh[(size_t)n * DD + col] = f2bf(acc * inv);
}

// ---------------- mega node MLP: B1 -> T -> u -> resid+LN -> (next nodeW1) ----------------
template<int FUSE>
__global__ __launch_bounds__(256) void k_mlp(
    const ushort* __restrict__ agg,
    const ushort* __restrict__ w2T, const float* __restrict__ b2,
    const float* __restrict__ flag,
    const ushort* __restrict__ u1T, const float* __restrict__ bu1,
    const ushort* __restrict__ u2T, const float* __restrict__ bu2,
    float* __restrict__ node,
    const float* __restrict__ lg, const float* __restrict__ lb,
    const ushort* __restrict__ w1nT, ushort* __restrict__ slotA, int M)
{
    __shared__ ushort tr[4][16 * 136];
    int tid = threadIdx.x, lane = tid & 63, w = tid >> 6;
    int base = (blockIdx.x * 4 + w) * 16;
    bool act = base < M;
    int cq = lane & 15, quad = lane >> 4;
    ushort* trw = tr[w];
    f4v acc[8];
    // stage 1: B1 = agg @ w2 + flag*b2  -> LDS
    if (act) {
        bf8v a[4];
        const ushort* Ab = agg + (size_t)(base + cq) * DD;
#pragma unroll
        for (int kc = 0; kc < 4; kc++)
            a[kc] = *(const bf8v*)(Ab + kc * 32 + quad * 8);
#pragma unroll
        for (int ct = 0; ct < 8; ct++) acc[ct] = 0.0f;
#pragma unroll
        for (int ct = 0; ct < 8; ct++) {
            const ushort* Wr = w2T + (size_t)(ct * 16 + cq) * DD;
#pragma unroll
            for (int kc = 0; kc < 4; kc++)
                acc[ct] = __builtin_amdgcn_mfma_f32_16x16x32_bf16(a[kc],
                    *(const bf8v*)(Wr + kc * 32 + quad * 8), acc[ct], 0, 0, 0);
        }
        float fl[4];
#pragma unroll
        for (int i = 0; i < 4; i++) fl[i] = flag[base + quad * 4 + i];
#pragma unroll
        for (int ct = 0; ct < 8; ct++) {
            int col = ct * 16 + cq;
            float b_ = b2[col];
#pragma unroll
            for (int i = 0; i < 4; i++)
                trw[(quad * 4 + i) * 136 + col] = f2bf(acc[ct][i] + fl[i] * b_);
        }
    }
    __syncthreads();
    bf8v a2[4];
    if (act) {
#pragma unroll
        for (int kc = 0; kc < 4; kc++)
            a2[kc] = *(const bf8v*)(trw + cq * 136 + kc * 32 + quad * 8);
    }
    f4v accU[8];
#pragma unroll
    for (int ct = 0; ct < 8; ct++) accU[ct] = 0.0f;
    // stage 2/3: two halves of T = gelu(B1@u1+b), accumulate u = T@u2
#pragma unroll
    for (int h = 0; h < 2; h++) {
        __syncthreads();
        if (act) {
#pragma unroll
            for (int ct = 0; ct < 8; ct++) acc[ct] = 0.0f;
#pragma unroll
            for (int ct = 0; ct < 8; ct++) {
                const ushort* Wr = u1T + (size_t)(h * 128 + ct * 16 + cq) * DD;
#pragma unroll
                for (int kc = 0; kc < 4; kc++)
                    acc[ct] = __builtin_amdgcn_mfma_f32_16x16x32_bf16(a2[kc],
                        *(const bf8v*)(Wr + kc * 32 + quad * 8), acc[ct], 0, 0, 0);
            }
#pragma unroll
            for (int ct = 0; ct < 8; ct++) {
                int col = ct * 16 + cq;
                float b_ = bu1[h * 128 + col];
#pragma unroll
                for (int i = 0; i < 4; i++)
                    trw[(quad * 4 + i) * 136 + col] = f2bf(gelu_f(acc[ct][i] + b_));
            }
        }
        __syncthreads();
        if (act) {
            bf8v tf[4];
#pragma unroll
            for (int kc = 0; kc < 4; kc++)
                tf[kc] = *(const bf8v*)(trw + cq * 136 + kc * 32 + quad * 8);
#pragma unroll
            for (int ct = 0; ct < 8; ct++) {
                const ushort* Wr = u2T + (size_t)(ct * 16 + cq) * 256 + h * 128;
#pragma unroll
                for (int kc = 0; kc < 4; kc++)
                    accU[ct] = __builtin_amdgcn_mfma_f32_16x16x32_bf16(tf[kc],
                        *(const bf8v*)(Wr + kc * 32 + quad * 8), accU[ct], 0, 0, 0);
            }
        }
    }
    // stage 4: residual + LN (+ stash LN output for fused next-layer GEMM)
    if (act) {
        int r0 = base + quad * 4;
        float xv[8][4], lgc[8], lbc[8];
#pragma unroll
        for (int ct = 0; ct < 8; ct++) {
            int col = ct * 16 + cq;
            float b_ = bu2[col];
            lgc[ct] = lg[col]; lbc[ct] = lb[col];
#pragma unroll
            for (int i = 0; i < 4; i++)
                xv[ct][i] = accU[ct][i] + b_ + node[(size_t)(r0 + i) * DD + col];
        }
#pragma unroll
        for (int i = 0; i < 4; i++) {
            float s = 0.0f;
#pragma unroll
            for (int ct = 0; ct < 8; ct++) s += xv[ct][i];
            s += __shfl_xor(s, 1); s += __shfl_xor(s, 2);
            s += __shfl_xor(s, 4); s += __shfl_xor(s, 8);
            float m = s * (1.0f / 128.0f);
            float vv = 0.0f;
#pragma unroll
            for (int ct = 0; ct < 8; ct++) { float d = xv[ct][i] - m; vv += d * d; }
            vv += __shfl_xor(vv, 1); vv += __shfl_xor(vv, 2);
            vv += __shfl_xor(vv, 4); vv += __shfl_xor(vv, 8);
            float inv = rsqrtf(vv * (1.0f / 128.0f) + 1e-5f);
#pragma unroll
            for (int ct = 0; ct < 8; ct++) {
                int col = ct * 16 + cq;
                float y = (xv[ct][i] - m) * inv * lgc[ct] + lbc[ct];
                node[(size_t)(r0 + i) * DD + col] = y;
                if (FUSE) trw[(quad * 4 + i) * 136 + col] = f2bf(y);
            }
        }
    }
    // stage 5: next layer's nodeW1 = LN(node) @ msg_w1[l+1]
    if (FUSE) {
        __syncthreads();
        if (act) {
            bf8v nf[4];
#pragma unroll
            for (int kc = 0; kc < 4; kc++)
                nf[kc] = *(const bf8v*)(trw + cq * 136 + kc * 32 + quad * 8);
#pragma unroll
            for (int ct = 0; ct < 8; ct++) acc[ct] = 0.0f;
#pragma unroll
            for (int ct = 0; ct < 8; ct++) {
                const ushort* Wr = w1nT + (size_t)(ct * 16 + cq) * DD;
#pragma unroll
                for (int kc = 0; kc < 4; kc++)
                    acc[ct] = __builtin_amdgcn_mfma_f32_16x16x32_bf16(nf[kc],
                        *(const bf8v*)(Wr + kc * 32 + quad * 8), acc[ct], 0, 0, 0);
            }
            int r0 = base + quad * 4;
#pragma unroll
            for (int ct = 0; ct < 8; ct++) {
                int col = ct * 16 + cq;
#pragma unroll
                for (int i = 0; i < 4; i++)
                    slotA[(size_t)(r0 + i) * DD + col] = f2bf(acc[ct][i]);
            }
        }
    }
}

// ---------------- pooling (fp32 node master) ----------------
__global__ void k_pool_partial(const float* __restrict__ node, float* __restrict__ partial) {
    int seg = blockIdx.x, chunk = blockIdx.y, j = threadIdx.x;
    int segbase = seg * 14286;
    int segcnt = (seg == 6) ? 14284 : 14286;
    int per = (segcnt + 15) / 16;
    int lo = chunk * per, hi = min(lo + per, segcnt);
    float s = 0.0f;
    for (int r = lo; r < hi; r++) s += node[(size_t)(segbase + r) * DD + j];
    partial[(seg * 16 + chunk) * DD + j] = s;
}

__global__ void k_pool_final(const float* __restrict__ partial, const float* __restrict__ g,
                             const float* __restrict__ b, float* __restrict__ out) {
    __shared__ float red[128];
    int j = threadIdx.x;
    float tok[8];
    float tot = 0.0f;
#pragma unroll
    for (int s = 0; s < 7; s++) {
        float v = 0.0f;
        for (int c = 0; c < 16; c++) v += partial[(s * 16 + c) * DD + j];
        tok[1 + s] = v / ((s == 6) ? 14284.0f : 14286.0f);
        tot += v;
    }
    tok[0] = tot / 100000.0f;
    for (int t = 0; t < 8; t++) {
        float x = tok[t];
        red[j] = x; __syncthreads();
        for (int off = 64; off > 0; off >>= 1) {
            if (j < off) red[j] += red[j + off];
            __syncthreads();
        }
        float m = red[0] / 128.0f;
        __syncthreads();
        float d = x - m;
        red[j] = d * d; __syncthreads();
        for (int off = 64; off > 0; off >>= 1) {
            if (j < off) red[j] += red[j + off];
            __syncthreads();
        }
        float var = red[0] / 128.0f;
        __syncthreads();
        out[t * DD + j] = d * rsqrtf(var + 1e-5f) * g[j] + b[j];
    }
}

extern "C" void kernel_launch(void* const* d_in, const int* in_sizes, int n_in,
                              void* d_out, int out_size, void* d_ws, size_t ws_size,
                              hipStream_t stream) {
    const float* x         = (const float*)d_in[0];
    const int*   ei        = (const int*)d_in[1];
    const float* edge_attr = (const float*)d_in[2];
    const float* node_w    = (const float*)d_in[3];
    const float* node_b    = (const float*)d_in[4];
    const float* edge_w    = (const float*)d_in[5];
    const float* edge_b    = (const float*)d_in[6];
    const float* msg_w1    = (const float*)d_in[7];
    const float* msg_b1    = (const float*)d_in[8];
    const float* msg_w2    = (const float*)d_in[9];
    const float* msg_b2    = (const float*)d_in[10];
    const float* upd_w1    = (const float*)d_in[11];
    const float* upd_b1    = (const float*)d_in[12];
    const float* upd_w2    = (const float*)d_in[13];
    const float* upd_b2    = (const float*)d_in[14];
    const float* ln_g      = (const float*)d_in[15];
    const float* ln_b      = (const float*)d_in[16];
    const float* out_g     = (const float*)d_in[17];
    const float* out_b     = (const float*)d_in[18];
    float* out = (float*)d_out;

    // ---- adaptive workspace layout (emb1h takes the remainder) ----
    char* pw = (char*)d_ws;
    auto alloc = [&](size_t bytes) -> void* {
        void* r = (void*)pw;
        pw += (bytes + 255) & ~(size_t)255;
        return r;
    };
    float*  node_f  = (float*) alloc((size_t)N_NODES * DD * 4);
    ushort* slotA   = (ushort*)alloc((size_t)N_NODES * DD * 2);
    ushort* aggb    = (ushort*)alloc((size_t)N_NODES * DD * 2);
    float*  We1     = (float*) alloc((size_t)3 * DE * DD * 4);
    float*  bc      = (float*) alloc((size_t)3 * DD * 4);
    ushort* WeT     = (ushort*)alloc((size_t)3 * DD * DE * 2);
    float*  partial = (float*) alloc((size_t)7 * 16 * DD * 4);
    float*  degflag = (float*) alloc((size_t)N_NODES * 4);
    ushort* node_wT = (ushort*)alloc((size_t)DD * DD * 2);
    ushort* msg_w1T = (ushort*)alloc((size_t)3 * DD * DD * 2);
    ushort* msg_w2T = (ushort*)alloc((size_t)3 * DD * DD * 2);
    ushort* upd_w1T = (ushort*)alloc((size_t)3 * 256 * DD * 2);
    ushort* upd_w2T = (ushort*)alloc((size_t)3 * DD * 256 * 2);
    int* cnt        = (int*)   alloc((size_t)N_NODES * 4);
    int* rowstart   = (int*)   alloc((size_t)(N_NODES + 1) * 4);
    int* cursor     = (int*)   alloc((size_t)N_NODES * 4);
    int* eord       = (int*)   alloc((size_t)N_EDGES * 4);
    int* esrc       = (int*)   alloc((size_t)N_EDGES * 4);
    ushort* emb1h   = (ushort*)pw;
    size_t avail = (ws_size > (size_t)(pw - (char*)d_ws)) ? ws_size - (size_t)(pw - (char*)d_ws) : 0;

    int P; size_t capE;
    if      (avail >= (size_t)N_EDGES * DD * 2)                 { P = 1; capE = N_EDGES; }
    else if (avail >= (size_t)(N_EDGES/2 + 60000) * DD * 2)     { P = 2; capE = N_EDGES/2 + 60000; }
    else if (avail >= (size_t)(N_EDGES/4 + 40000) * DD * 2)     { P = 4; capE = N_EDGES/4 + 40000; }
    else                                                        { P = 8; capE = avail / (DD * 2); }

    hipMemsetAsync(cnt, 0, N_NODES * sizeof(int), stream);
    k_count  <<<(N_EDGES + 255) / 256, 256, 0, stream>>>(ei, cnt);
    k_scan   <<<1, 1024, 0, stream>>>(cnt, rowstart);
    k_cursor <<<(N_NODES + 255) / 256, 256, 0, stream>>>(rowstart, cursor);
    k_scatter<<<(N_EDGES + 255) / 256, 256, 0, stream>>>(ei, cursor, eord, esrc);
    k_degflag<<<(N_NODES + 255) / 256, 256, 0, stream>>>(rowstart, degflag);
    k_prep   <<<dim3(DE + 1, 3), DD, 0, stream>>>(edge_w, edge_b, msg_w1, msg_b1, We1, bc);

    // weight transposes -> bf16 [out][in]
    k_tbf<<<(DD*DD + 255)/256, 256, 0, stream>>>(node_w, node_wT, DD, DD);
    for (int l = 0; l < 3; l++) {
        k_tbf<<<(DD*DD + 255)/256, 256, 0, stream>>>(msg_w1 + (size_t)l*DD*DD, msg_w1T + (size_t)l*DD*DD, DD, DD);
        k_tbf<<<(DD*DD + 255)/256, 256, 0, stream>>>(msg_w2 + (size_t)l*DD*DD, msg_w2T + (size_t)l*DD*DD, DD, DD);
        k_tbf<<<(DD*256 + 255)/256, 256, 0, stream>>>(upd_w1 + (size_t)l*DD*256, upd_w1T + (size_t)l*256*DD, DD, 256);
        k_tbf<<<(256*DD + 255)/256, 256, 0, stream>>>(upd_w2 + (size_t)l*256*DD, upd_w2T + (size_t)l*DD*256, 256, DD);
        k_tbf<<<(DE*DD + 255)/256, 256, 0, stream>>>(We1 + (size_t)l*DE*DD, WeT + (size_t)l*DD*DE, DE, DD);
    }

    const int GB = (N_NODES / 16 + 3) / 4;  // 1563
    // embed + fused nodeW1 for layer 0
    k_embed<<<GB, 256, 0, stream>>>(x, node_wT, node_b, msg_w1T, node_f, slotA, N_NODES);

    for (int l = 0; l < 3; l++) {
        for (int pI = 0; pI < P; pI++) {
            int n_lo = (int)((long long)N_NODES * pI / P);
            int n_hi = (int)((long long)N_NODES * (pI + 1) / P);
            int gb1 = (int)((capE + 63) / 64);
            k_emb1<<<gb1, 256, 0, stream>>>(eord, edge_attr, WeT + (size_t)l*DD*DE,
                bc + (size_t)l*DD, rowstart, n_lo, n_hi, (int)capE, emb1h);
            k_edge<<<(n_hi - n_lo + 1) / 2, 256, 0, stream>>>(emb1h, slotA, esrc, rowstart,
                n_lo, n_hi, (int)capE, aggb);
        }
        if (l < 2) {
            k_mlp<1><<<GB, 256, 0, stream>>>(aggb,
                msg_w2T + (size_t)l*DD*DD, msg_b2 + (size_t)l*DD, degflag,
                upd_w1T + (size_t)l*256*DD, upd_b1 + (size_t)l*256,
                upd_w2T + (size_t)l*DD*256, upd_b2 + (size_t)l*DD,
                node_f, ln_g + (size_t)l*DD, ln_b + (size_t)l*DD,
                msg_w1T + (size_t)(l+1)*DD*DD, slotA, N_NODES);
        } else {
            k_mlp<0><<<GB, 256, 0, stream>>>(aggb,
                msg_w2T + (size_t)l*DD*DD, msg_b2 + (size_t)l*DD, degflag,
                upd_w1T + (size_t)l*256*DD, upd_b1 + (size_t)l*256,
                upd_w2T + (size_t)l*DD*256, upd_b2 + (size_t)l*DD,
                node_f, ln_g + (size_t)l*DD, ln_b + (size_t)l*DD,
                msg_w1T, slotA, N_NODES);
        }
    }

    k_pool_partial<<<dim3(7, 16), DD, 0, stream>>>(node_f, partial);
    k_pool_final  <<<1, DD, 0, stream>>>(partial, out_g, out_b, out);
}

// Round 6
// 1654.407 us; speedup vs baseline: 1.1518x; 1.1084x over previous
//
#include <hip/hip_runtime.h>
#include <hip/hip_bf16.h>

#define N_NODES 100000
#define N_EDGES 640000
#define DD 128
#define DE 32

typedef __attribute__((ext_vector_type(8))) short bf8v;
typedef __attribute__((ext_vector_type(4))) float f4v;

__device__ __forceinline__ float gelu_f(float x) {
    return 0.5f * x * (1.0f + erff(x * 0.70710678118654752f));
}
__device__ __forceinline__ float gelu_t(float x) {
    float y = 0.7978845608f * (x + 0.044715f * x * x * x);
    float t = __expf(-2.0f * fabsf(y));
    float th = (1.0f - t) / (1.0f + t);
    th = copysignf(th, y);
    return 0.5f * x * (1.0f + th);
}
__device__ __forceinline__ float bf2f(ushort u) {
    union { uint u; float f; } t; t.u = ((uint)u) << 16; return t.f;
}
__device__ __forceinline__ ushort f2bf(float f) {
    union { float f; uint u; } t; t.f = f;
    uint r = (t.u + 0x7fffu + ((t.u >> 16) & 1u)) >> 16;
    return (ushort)r;
}

// ---------------- CSR build ----------------
__global__ void k_count(const int* __restrict__ ei, int* __restrict__ cnt) {
    int e = blockIdx.x * blockDim.x + threadIdx.x;
    if (e < N_EDGES) atomicAdd(&cnt[ei[N_EDGES + e]], 1);
}

// scan + cursor init + degflag in one kernel
__global__ void k_scan(const int* __restrict__ cnt, int* __restrict__ rowstart,
                       int* __restrict__ cursor, float* __restrict__ flag) {
    __shared__ int part[1024];
    int t = threadIdx.x;
    const int chunk = (N_NODES + 1023) / 1024;
    int lo = t * chunk, hi = min(lo + chunk, N_NODES);
    int s = 0;
    for (int i = lo; i < hi; i++) s += cnt[i];
    part[t] = s;
    __syncthreads();
    for (int off = 1; off < 1024; off <<= 1) {
        int v = (t >= off) ? part[t - off] : 0;
        __syncthreads();
        part[t] += v;
        __syncthreads();
    }
    int run = (t == 0) ? 0 : part[t - 1];
    for (int i = lo; i < hi; i++) {
        int c = cnt[i];
        rowstart[i] = run;
        cursor[i] = run;
        flag[i] = (c > 0) ? 1.0f : 0.0f;
        run += c;
    }
    if (lo < N_NODES && hi == N_NODES) rowstart[N_NODES] = run;
}

__global__ void k_scatter(const int* __restrict__ ei, int* __restrict__ cursor,
                          int* __restrict__ eord, int* __restrict__ esrc) {
    int e = blockIdx.x * blockDim.x + threadIdx.x;
    if (e < N_EDGES) {
        int pos = atomicAdd(&cursor[ei[N_EDGES + e]], 1);
        eord[pos] = e;
        esrc[pos] = ei[e];
    }
}

// ---------------- composite edge weights: writes bf16-transposed WeT + fp32 bc ----------------
__global__ void k_prep(const float* __restrict__ edge_w, const float* __restrict__ edge_b,
                       const float* __restrict__ msg_w1, const float* __restrict__ msg_b1,
                       ushort* __restrict__ WeT, float* __restrict__ bc) {
    int j = threadIdx.x;
    int c = blockIdx.x;
    int l = blockIdx.y;
    const float* w1 = msg_w1 + (size_t)l * DD * DD;
    if (c < DE) {
        float s = 0.0f;
        for (int k = 0; k < DD; k++) s += edge_w[c*DD + k] * w1[k*DD + j];
        WeT[((size_t)l*DD + j)*DE + c] = f2bf(s);     // [l][j(out)][c(k)]
    } else {
        float s = msg_b1[l*DD + j];
        for (int k = 0; k < DD; k++) s += edge_b[k] * w1[k*DD + j];
        bc[l*DD + j] = s;
    }
}

// ---------------- batched transpose fp32 [R][C] -> bf16 [C][R] ----------------
struct TDesc { const float* src; ushort* dst; int R; int C; };
struct TPack { TDesc d[13]; };

__global__ void k_tball(TPack p) {
    TDesc t = p.d[blockIdx.y];
    int idx = blockIdx.x * 256 + threadIdx.x;
    if (idx < t.R * t.C) {
        int r = idx / t.C, c = idx % t.C;
        t.dst[(size_t)c * t.R + r] = f2bf(t.src[idx]);
    }
}

// ---------------- embed + fused nodeW1(l=0) ----------------
__global__ __launch_bounds__(256) void k_embed(
    const float* __restrict__ x, const ushort* __restrict__ WT,
    const float* __restrict__ bias, const ushort* __restrict__ W1T,
    float* __restrict__ node, ushort* __restrict__ slotA, int M)
{
    __shared__ ushort tr[4][16 * 136];
    int tid = threadIdx.x, lane = tid & 63, w = tid >> 6;
    int base = (blockIdx.x * 4 + w) * 16;
    bool act = base < M;
    int cq = lane & 15, quad = lane >> 4;
    ushort* trw = tr[w];
    f4v acc[8];
    if (act) {
        bf8v a[4];
        const float* Af = x + (size_t)(base + cq) * DD;
#pragma unroll
        for (int kc = 0; kc < 4; kc++) {
            float4 v0 = *(const float4*)(Af + kc * 32 + quad * 8);
            float4 v1 = *(const float4*)(Af + kc * 32 + quad * 8 + 4);
            bf8v t;
            t[0]=(short)f2bf(v0.x); t[1]=(short)f2bf(v0.y); t[2]=(short)f2bf(v0.z); t[3]=(short)f2bf(v0.w);
            t[4]=(short)f2bf(v1.x); t[5]=(short)f2bf(v1.y); t[6]=(short)f2bf(v1.z); t[7]=(short)f2bf(v1.w);
            a[kc] = t;
        }
#pragma unroll
        for (int ct = 0; ct < 8; ct++) acc[ct] = 0.0f;
#pragma unroll
        for (int ct = 0; ct < 8; ct++) {
            const ushort* Wr = WT + (size_t)(ct * 16 + cq) * DD;
#pragma unroll
            for (int kc = 0; kc < 4; kc++)
                acc[ct] = __builtin_amdgcn_mfma_f32_16x16x32_bf16(a[kc],
                    *(const bf8v*)(Wr + kc * 32 + quad * 8), acc[ct], 0, 0, 0);
        }
        int r0 = base + quad * 4;
#pragma unroll
        for (int ct = 0; ct < 8; ct++) {
            int col = ct * 16 + cq;
            float b_ = bias[col];
#pragma unroll
            for (int i = 0; i < 4; i++) {
                float v = acc[ct][i] + b_;
                node[(size_t)(r0 + i) * DD + col] = v;
                trw[(quad * 4 + i) * 136 + col] = f2bf(v);
            }
        }
    }
    __syncthreads();
    if (act) {
        bf8v a2[4];
#pragma unroll
        for (int kc = 0; kc < 4; kc++)
            a2[kc] = *(const bf8v*)(trw + cq * 136 + kc * 32 + quad * 8);
#pragma unroll
        for (int ct = 0; ct < 8; ct++) acc[ct] = 0.0f;
#pragma unroll
        for (int ct = 0; ct < 8; ct++) {
            const ushort* Wr = W1T + (size_t)(ct * 16 + cq) * DD;
#pragma unroll
            for (int kc = 0; kc < 4; kc++)
                acc[ct] = __builtin_amdgcn_mfma_f32_16x16x32_bf16(a2[kc],
                    *(const bf8v*)(Wr + kc * 32 + quad * 8), acc[ct], 0, 0, 0);
        }
        int r0 = base + quad * 4;
#pragma unroll
        for (int ct = 0; ct < 8; ct++) {
            int col = ct * 16 + cq;
#pragma unroll
            for (int i = 0; i < 4; i++)
                slotA[(size_t)(r0 + i) * DD + col] = f2bf(acc[ct][i]);
        }
    }
}

// ---------------- per-edge embedding MLP (MFMA, K=32), CSR order, node-range pass ----------------
__global__ __launch_bounds__(256) void k_emb1(
    const int* __restrict__ eord, const float* __restrict__ edge_attr,
    const ushort* __restrict__ WeT, const float* __restrict__ bcv,
    const int* __restrict__ rowstart, int n_lo, int n_hi, int cap,
    ushort* __restrict__ emb1h)
{
    __shared__ ushort tr[4][16 * 136];
    int tid = threadIdx.x, lane = tid & 63, w = tid >> 6;
    int tbase = (blockIdx.x * 4 + w) * 16;
    int cq = lane & 15, quad = lane >> 4;
    int j_lo = rowstart[n_lo], j_hi = rowstart[n_hi];
    int cnt = j_hi - j_lo; if (cnt > cap) cnt = cap;
    ushort* trw = tr[w];
    bool act = tbase < cnt;
    if (act) {
        int jl = tbase + cq;
        bf8v a;
#pragma unroll
        for (int t = 0; t < 8; t++) a[t] = 0;
        if (jl < cnt) {
            int e = eord[j_lo + jl];
            const float* ea = edge_attr + (size_t)e * DE + quad * 8;
            float4 v0 = *(const float4*)(ea);
            float4 v1 = *(const float4*)(ea + 4);
            a[0]=(short)f2bf(v0.x); a[1]=(short)f2bf(v0.y); a[2]=(short)f2bf(v0.z); a[3]=(short)f2bf(v0.w);
            a[4]=(short)f2bf(v1.x); a[5]=(short)f2bf(v1.y); a[6]=(short)f2bf(v1.z); a[7]=(short)f2bf(v1.w);
        }
#pragma unroll
        for (int ct = 0; ct < 8; ct++) {
            bf8v b = *(const bf8v*)(WeT + (size_t)(ct * 16 + cq) * DE + quad * 8);
            f4v z; z = 0.0f;
            f4v r = __builtin_amdgcn_mfma_f32_16x16x32_bf16(a, b, z, 0, 0, 0);
            int col = ct * 16 + cq;
            float b_ = bcv[col];
#pragma unroll
            for (int i = 0; i < 4; i++)
                trw[(quad * 4 + i) * 136 + col] = f2bf(r[i] + b_);
        }
    }
    __syncthreads();
    if (act) {
        int r = lane >> 2, ch = (lane & 3) * 32;
        int jl = tbase + r;
        if (jl < cnt) {
#pragma unroll
            for (int q = 0; q < 4; q++) {
                bf8v v = *(const bf8v*)(trw + r * 136 + ch + q * 8);
                *(bf8v*)(emb1h + (size_t)jl * DD + ch + q * 8) = v;
            }
        }
    }
}

// ---------------- lean edge aggregation: 1 wave/node, 2 cols/lane, uint loads ----------------
__global__ __launch_bounds__(256) void k_edge(
    const ushort* __restrict__ emb1h, const ushort* __restrict__ nodeW1,
    const int* __restrict__ esrc, const int* __restrict__ rowstart,
    int n_lo, int n_hi, int cap, ushort* __restrict__ aggh)
{
    int lane = threadIdx.x & 63;
    int w = threadIdx.x >> 6;
    int n = n_lo + blockIdx.x * 4 + w;
    if (n >= n_hi) return;
    int j_lo = rowstart[n_lo];
    int rs = rowstart[n], re0 = rowstart[n + 1];
    int lim = j_lo + cap;
    int re = (re0 > lim) ? lim : re0;
    float a0 = 0.0f, a1 = 0.0f;
    int j = rs;
    for (; j + 1 < re; j += 2) {
        int s0 = __builtin_amdgcn_readfirstlane(esrc[j]);
        int s1 = __builtin_amdgcn_readfirstlane(esrc[j + 1]);
        uint e0 = *(const uint*)(emb1h + (size_t)(j - j_lo) * DD + 2 * lane);
        uint e1 = *(const uint*)(emb1h + (size_t)(j + 1 - j_lo) * DD + 2 * lane);
        uint n0 = *(const uint*)(nodeW1 + (size_t)s0 * DD + 2 * lane);
        uint n1 = *(const uint*)(nodeW1 + (size_t)s1 * DD + 2 * lane);
        a0 += gelu_t(bf2f((ushort)(e0 & 0xffffu)) + bf2f((ushort)(n0 & 0xffffu)))
            + gelu_t(bf2f((ushort)(e1 & 0xffffu)) + bf2f((ushort)(n1 & 0xffffu)));
        a1 += gelu_t(bf2f((ushort)(e0 >> 16)) + bf2f((ushort)(n0 >> 16)))
            + gelu_t(bf2f((ushort)(e1 >> 16)) + bf2f((ushort)(n1 >> 16)));
    }
    if (j < re) {
        int s0 = __builtin_amdgcn_readfirstlane(esrc[j]);
        uint e0 = *(const uint*)(emb1h + (size_t)(j - j_lo) * DD + 2 * lane);
        uint n0 = *(const uint*)(nodeW1 + (size_t)s0 * DD + 2 * lane);
        a0 += gelu_t(bf2f((ushort)(e0 & 0xffffu)) + bf2f((ushort)(n0 & 0xffffu)));
        a1 += gelu_t(bf2f((ushort)(e0 >> 16)) + bf2f((ushort)(n0 >> 16)));
    }
    int deg = re0 - rs;
    float inv = (deg > 0) ? 1.0f / (float)deg : 0.0f;
    uint o = (uint)f2bf(a0 * inv) | ((uint)f2bf(a1 * inv) << 16);
    *(uint*)(aggh + (size_t)n * DD + 2 * lane) = o;
}

// ---------------- mega node MLP: B1 -> T -> u -> resid+LN -> (next nodeW1) ----------------
template<int FUSE>
__global__ __launch_bounds__(256) void k_mlp(
    const ushort* __restrict__ agg,
    const ushort* __restrict__ w2T, const float* __restrict__ b2,
    const float* __restrict__ flag,
    const ushort* __restrict__ u1T, const float* __restrict__ bu1,
    const ushort* __restrict__ u2T, const float* __restrict__ bu2,
    float* __restrict__ node,
    const float* __restrict__ lg, const float* __restrict__ lb,
    const ushort* __restrict__ w1nT, ushort* __restrict__ slotA, int M)
{
    __shared__ ushort tr[4][16 * 136];
    int tid = threadIdx.x, lane = tid & 63, w = tid >> 6;
    int base = (blockIdx.x * 4 + w) * 16;
    bool act = base < M;
    int cq = lane & 15, quad = lane >> 4;
    ushort* trw = tr[w];
    f4v acc[8];
    if (act) {
        bf8v a[4];
        const ushort* Ab = agg + (size_t)(base + cq) * DD;
#pragma unroll
        for (int kc = 0; kc < 4; kc++)
            a[kc] = *(const bf8v*)(Ab + kc * 32 + quad * 8);
#pragma unroll
        for (int ct = 0; ct < 8; ct++) acc[ct] = 0.0f;
#pragma unroll
        for (int ct = 0; ct < 8; ct++) {
            const ushort* Wr = w2T + (size_t)(ct * 16 + cq) * DD;
#pragma unroll
            for (int kc = 0; kc < 4; kc++)
                acc[ct] = __builtin_amdgcn_mfma_f32_16x16x32_bf16(a[kc],
                    *(const bf8v*)(Wr + kc * 32 + quad * 8), acc[ct], 0, 0, 0);
        }
        float fl[4];
#pragma unroll
        for (int i = 0; i < 4; i++) fl[i] = flag[base + quad * 4 + i];
#pragma unroll
        for (int ct = 0; ct < 8; ct++) {
            int col = ct * 16 + cq;
            float b_ = b2[col];
#pragma unroll
            for (int i = 0; i < 4; i++)
                trw[(quad * 4 + i) * 136 + col] = f2bf(acc[ct][i] + fl[i] * b_);
        }
    }
    __syncthreads();
    bf8v a2[4];
    if (act) {
#pragma unroll
        for (int kc = 0; kc < 4; kc++)
            a2[kc] = *(const bf8v*)(trw + cq * 136 + kc * 32 + quad * 8);
    }
    f4v accU[8];
#pragma unroll
    for (int ct = 0; ct < 8; ct++) accU[ct] = 0.0f;
#pragma unroll
    for (int h = 0; h < 2; h++) {
        __syncthreads();
        if (act) {
#pragma unroll
            for (int ct = 0; ct < 8; ct++) acc[ct] = 0.0f;
#pragma unroll
            for (int ct = 0; ct < 8; ct++) {
                const ushort* Wr = u1T + (size_t)(h * 128 + ct * 16 + cq) * DD;
#pragma unroll
                for (int kc = 0; kc < 4; kc++)
                    acc[ct] = __builtin_amdgcn_mfma_f32_16x16x32_bf16(a2[kc],
                        *(const bf8v*)(Wr + kc * 32 + quad * 8), acc[ct], 0, 0, 0);
            }
#pragma unroll
            for (int ct = 0; ct < 8; ct++) {
                int col = ct * 16 + cq;
                float b_ = bu1[h * 128 + col];
#pragma unroll
                for (int i = 0; i < 4; i++)
                    trw[(quad * 4 + i) * 136 + col] = f2bf(gelu_f(acc[ct][i] + b_));
            }
        }
        __syncthreads();
        if (act) {
            bf8v tf[4];
#pragma unroll
            for (int kc = 0; kc < 4; kc++)
                tf[kc] = *(const bf8v*)(trw + cq * 136 + kc * 32 + quad * 8);
#pragma unroll
            for (int ct = 0; ct < 8; ct++) {
                const ushort* Wr = u2T + (size_t)(ct * 16 + cq) * 256 + h * 128;
#pragma unroll
                for (int kc = 0; kc < 4; kc++)
                    accU[ct] = __builtin_amdgcn_mfma_f32_16x16x32_bf16(tf[kc],
                        *(const bf8v*)(Wr + kc * 32 + quad * 8), accU[ct], 0, 0, 0);
            }
        }
    }
    if (act) {
        int r0 = base + quad * 4;
        float xv[8][4], lgc[8], lbc[8];
#pragma unroll
        for (int ct = 0; ct < 8; ct++) {
            int col = ct * 16 + cq;
            float b_ = bu2[col];
            lgc[ct] = lg[col]; lbc[ct] = lb[col];
#pragma unroll
            for (int i = 0; i < 4; i++)
                xv[ct][i] = accU[ct][i] + b_ + node[(size_t)(r0 + i) * DD + col];
        }
#pragma unroll
        for (int i = 0; i < 4; i++) {
            float s = 0.0f;
#pragma unroll
            for (int ct = 0; ct < 8; ct++) s += xv[ct][i];
            s += __shfl_xor(s, 1); s += __shfl_xor(s, 2);
            s += __shfl_xor(s, 4); s += __shfl_xor(s, 8);
            float m = s * (1.0f / 128.0f);
            float vv = 0.0f;
#pragma unroll
            for (int ct = 0; ct < 8; ct++) { float d = xv[ct][i] - m; vv += d * d; }
            vv += __shfl_xor(vv, 1); vv += __shfl_xor(vv, 2);
            vv += __shfl_xor(vv, 4); vv += __shfl_xor(vv, 8);
            float inv = rsqrtf(vv * (1.0f / 128.0f) + 1e-5f);
#pragma unroll
            for (int ct = 0; ct < 8; ct++) {
                int col = ct * 16 + cq;
                float y = (xv[ct][i] - m) * inv * lgc[ct] + lbc[ct];
                node[(size_t)(r0 + i) * DD + col] = y;
                if (FUSE) trw[(quad * 4 + i) * 136 + col] = f2bf(y);
            }
        }
    }
    if (FUSE) {
        __syncthreads();
        if (act) {
            bf8v nf[4];
#pragma unroll
            for (int kc = 0; kc < 4; kc++)
                nf[kc] = *(const bf8v*)(trw + cq * 136 + kc * 32 + quad * 8);
#pragma unroll
            for (int ct = 0; ct < 8; ct++) acc[ct] = 0.0f;
#pragma unroll
            for (int ct = 0; ct < 8; ct++) {
                const ushort* Wr = w1nT + (size_t)(ct * 16 + cq) * DD;
#pragma unroll
                for (int kc = 0; kc < 4; kc++)
                    acc[ct] = __builtin_amdgcn_mfma_f32_16x16x32_bf16(nf[kc],
                        *(const bf8v*)(Wr + kc * 32 + quad * 8), acc[ct], 0, 0, 0);
            }
            int r0 = base + quad * 4;
#pragma unroll
            for (int ct = 0; ct < 8; ct++) {
                int col = ct * 16 + cq;
#pragma unroll
                for (int i = 0; i < 4; i++)
                    slotA[(size_t)(r0 + i) * DD + col] = f2bf(acc[ct][i]);
            }
        }
    }
}

// ---------------- pooling: 128 chunks/segment for latency hiding ----------------
__global__ void k_pool_partial(const float* __restrict__ node, float* __restrict__ partial) {
    int seg = blockIdx.x, chunk = blockIdx.y, j = threadIdx.x;
    int segbase = seg * 14286;
    int segcnt = (seg == 6) ? 14284 : 14286;
    const int per = 112;                       // ceil(14286/128)
    int lo = chunk * per, hi = min(lo + per, segcnt);
    float s = 0.0f;
    for (int r = lo; r < hi; r++) s += node[(size_t)(segbase + r) * DD + j];
    partial[(size_t)(seg * 128 + chunk) * DD + j] = s;
}

__global__ void k_pool_final(const float* __restrict__ partial, const float* __restrict__ g,
                             const float* __restrict__ b, float* __restrict__ out) {
    __shared__ float red[128];
    int j = threadIdx.x;
    float tok[8];
    float tot = 0.0f;
#pragma unroll
    for (int s = 0; s < 7; s++) {
        float v = 0.0f;
        for (int c = 0; c < 128; c++) v += partial[(size_t)(s * 128 + c) * DD + j];
        tok[1 + s] = v / ((s == 6) ? 14284.0f : 14286.0f);
        tot += v;
    }
    tok[0] = tot / 100000.0f;
    for (int t = 0; t < 8; t++) {
        float x = tok[t];
        red[j] = x; __syncthreads();
        for (int off = 64; off > 0; off >>= 1) {
            if (j < off) red[j] += red[j + off];
            __syncthreads();
        }
        float m = red[0] / 128.0f;
        __syncthreads();
        float d = x - m;
        red[j] = d * d; __syncthreads();
        for (int off = 64; off > 0; off >>= 1) {
            if (j < off) red[j] += red[j + off];
            __syncthreads();
        }
        float var = red[0] / 128.0f;
        __syncthreads();
        out[t * DD + j] = d * rsqrtf(var + 1e-5f) * g[j] + b[j];
    }
}

extern "C" void kernel_launch(void* const* d_in, const int* in_sizes, int n_in,
                              void* d_out, int out_size, void* d_ws, size_t ws_size,
                              hipStream_t stream) {
    const float* x         = (const float*)d_in[0];
    const int*   ei        = (const int*)d_in[1];
    const float* edge_attr = (const float*)d_in[2];
    const float* node_w    = (const float*)d_in[3];
    const float* node_b    = (const float*)d_in[4];
    const float* edge_w    = (const float*)d_in[5];
    const float* edge_b    = (const float*)d_in[6];
    const float* msg_w1    = (const float*)d_in[7];
    const float* msg_b1    = (const float*)d_in[8];
    const float* msg_w2    = (const float*)d_in[9];
    const float* msg_b2    = (const float*)d_in[10];
    const float* upd_w1    = (const float*)d_in[11];
    const float* upd_b1    = (const float*)d_in[12];
    const float* upd_w2    = (const float*)d_in[13];
    const float* upd_b2    = (const float*)d_in[14];
    const float* ln_g      = (const float*)d_in[15];
    const float* ln_b      = (const float*)d_in[16];
    const float* out_g     = (const float*)d_in[17];
    const float* out_b     = (const float*)d_in[18];
    float* out = (float*)d_out;

    // ---- workspace layout (emb1h takes the remainder) ----
    char* pw = (char*)d_ws;
    auto alloc = [&](size_t bytes) -> void* {
        void* r = (void*)pw;
        pw += (bytes + 255) & ~(size_t)255;
        return r;
    };
    float*  node_f  = (float*) alloc((size_t)N_NODES * DD * 4);
    ushort* slotA   = (ushort*)alloc((size_t)N_NODES * DD * 2);
    ushort* aggb    = (ushort*)alloc((size_t)N_NODES * DD * 2);
    float*  bc      = (float*) alloc((size_t)3 * DD * 4);
    ushort* WeT     = (ushort*)alloc((size_t)3 * DD * DE * 2);
    float*  partial = (float*) alloc((size_t)7 * 128 * DD * 4);
    float*  degflag = (float*) alloc((size_t)N_NODES * 4);
    ushort* node_wT = (ushort*)alloc((size_t)DD * DD * 2);
    ushort* msg_w1T = (ushort*)alloc((size_t)3 * DD * DD * 2);
    ushort* msg_w2T = (ushort*)alloc((size_t)3 * DD * DD * 2);
    ushort* upd_w1T = (ushort*)alloc((size_t)3 * 256 * DD * 2);
    ushort* upd_w2T = (ushort*)alloc((size_t)3 * DD * 256 * 2);
    int* cnt        = (int*)   alloc((size_t)N_NODES * 4);
    int* rowstart   = (int*)   alloc((size_t)(N_NODES + 1) * 4);
    int* cursor     = (int*)   alloc((size_t)N_NODES * 4);
    int* eord       = (int*)   alloc((size_t)N_EDGES * 4);
    int* esrc       = (int*)   alloc((size_t)N_EDGES * 4);
    ushort* emb1h   = (ushort*)pw;
    size_t avail = (ws_size > (size_t)(pw - (char*)d_ws)) ? ws_size - (size_t)(pw - (char*)d_ws) : 0;

    // prefer P=2 (chunk ~82 MB stays L3-resident between k_emb1 write and k_edge read)
    int P; size_t capE;
    if      (avail >= (size_t)(N_EDGES/2 + 60000) * DD * 2)     { P = 2; capE = N_EDGES/2 + 60000; }
    else if (avail >= (size_t)(N_EDGES/4 + 40000) * DD * 2)     { P = 4; capE = N_EDGES/4 + 40000; }
    else                                                        { P = 8; capE = avail / (DD * 2); }

    hipMemsetAsync(cnt, 0, N_NODES * sizeof(int), stream);
    k_count  <<<(N_EDGES + 255) / 256, 256, 0, stream>>>(ei, cnt);
    k_scan   <<<1, 1024, 0, stream>>>(cnt, rowstart, cursor, degflag);
    k_scatter<<<(N_EDGES + 255) / 256, 256, 0, stream>>>(ei, cursor, eord, esrc);
    k_prep   <<<dim3(DE + 1, 3), DD, 0, stream>>>(edge_w, edge_b, msg_w1, msg_b1, WeT, bc);

    // batched weight transposes -> bf16 [out][in]
    TPack tp;
    tp.d[0] = { node_w, node_wT, DD, DD };
    for (int l = 0; l < 3; l++) {
        tp.d[1 + l*4 + 0] = { msg_w1 + (size_t)l*DD*DD,  msg_w1T + (size_t)l*DD*DD,  DD, DD };
        tp.d[1 + l*4 + 1] = { msg_w2 + (size_t)l*DD*DD,  msg_w2T + (size_t)l*DD*DD,  DD, DD };
        tp.d[1 + l*4 + 2] = { upd_w1 + (size_t)l*DD*256, upd_w1T + (size_t)l*256*DD, DD, 256 };
        tp.d[1 + l*4 + 3] = { upd_w2 + (size_t)l*256*DD, upd_w2T + (size_t)l*DD*256, 256, DD };
    }
    k_tball<<<dim3(128, 13), 256, 0, stream>>>(tp);

    const int GB = (N_NODES / 16 + 3) / 4;  // 1563
    k_embed<<<GB, 256, 0, stream>>>(x, node_wT, node_b, msg_w1T, node_f, slotA, N_NODES);

    for (int l = 0; l < 3; l++) {
        for (int pI = 0; pI < P; pI++) {
            int n_lo = (int)((long long)N_NODES * pI / P);
            int n_hi = (int)((long long)N_NODES * (pI + 1) / P);
            int gb1 = (int)((capE + 63) / 64);
            k_emb1<<<gb1, 256, 0, stream>>>(eord, edge_attr, WeT + (size_t)l*DD*DE,
                bc + (size_t)l*DD, rowstart, n_lo, n_hi, (int)capE, emb1h);
            k_edge<<<(n_hi - n_lo + 3) / 4, 256, 0, stream>>>(emb1h, slotA, esrc, rowstart,
                n_lo, n_hi, (int)capE, aggb);
        }
        if (l < 2) {
            k_mlp<1><<<GB, 256, 0, stream>>>(aggb,
                msg_w2T + (size_t)l*DD*DD, msg_b2 + (size_t)l*DD, degflag,
                upd_w1T + (size_t)l*256*DD, upd_b1 + (size_t)l*256,
                upd_w2T + (size_t)l*DD*256, upd_b2 + (size_t)l*DD,
                node_f, ln_g + (size_t)l*DD, ln_b + (size_t)l*DD,
                msg_w1T + (size_t)(l+1)*DD*DD, slotA, N_NODES);
        } else {
            k_mlp<0><<<GB, 256, 0, stream>>>(aggb,
                msg_w2T + (size_t)l*DD*DD, msg_b2 + (size_t)l*DD, degflag,
                upd_w1T + (size_t)l*256*DD, upd_b1 + (size_t)l*256,
                upd_w2T + (size_t)l*DD*256, upd_b2 + (size_t)l*DD,
                node_f, ln_g + (size_t)l*DD, ln_b + (size_t)l*DD,
                msg_w1T, slotA, N_NODES);
        }
    }

    k_pool_partial<<<dim3(7, 128), DD, 0, stream>>>(node_f, partial);
    k_pool_final  <<<1, DD, 0, stream>>>(partial, out_g, out_b, out);
}

// Round 7
// 1452.554 us; speedup vs baseline: 1.3118x; 1.1390x over previous
//
#include <hip/hip_runtime.h>
#include <hip/hip_bf16.h>

#define N_NODES 100000
#define N_EDGES 640000
#define DD 128
#define DE 32
#define SCAN_B 256
#define SCAN_NB ((N_NODES + SCAN_B - 1) / SCAN_B)   // 391

typedef __attribute__((ext_vector_type(8))) short bf8v;
typedef __attribute__((ext_vector_type(4))) float f4v;

__device__ __forceinline__ float gelu_f(float x) {
    return 0.5f * x * (1.0f + erff(x * 0.70710678118654752f));
}
__device__ __forceinline__ float gelu_t(float x) {
    float y = 0.7978845608f * (x + 0.044715f * x * x * x);
    float t = __expf(-2.0f * fabsf(y));
    float th = (1.0f - t) / (1.0f + t);
    th = copysignf(th, y);
    return 0.5f * x * (1.0f + th);
}
__device__ __forceinline__ float bf2f(ushort u) {
    union { uint u; float f; } t; t.u = ((uint)u) << 16; return t.f;
}
__device__ __forceinline__ ushort f2bf(float f) {
    union { float f; uint u; } t; t.f = f;
    uint r = (t.u + 0x7fffu + ((t.u >> 16) & 1u)) >> 16;
    return (ushort)r;
}

// ---------------- CSR build ----------------
__global__ void k_count(const int* __restrict__ ei, int* __restrict__ cnt) {
    int e = blockIdx.x * blockDim.x + threadIdx.x;
    if (e < N_EDGES) atomicAdd(&cnt[ei[N_EDGES + e]], 1);
}

// phase 1: per-block sums
__global__ void k_scan1(const int* __restrict__ cnt, int* __restrict__ bsum) {
    __shared__ int s[SCAN_B];
    int i = blockIdx.x * SCAN_B + threadIdx.x;
    int v = (i < N_NODES) ? cnt[i] : 0;
    s[threadIdx.x] = v;
    __syncthreads();
    for (int off = SCAN_B / 2; off > 0; off >>= 1) {
        if (threadIdx.x < off) s[threadIdx.x] += s[threadIdx.x + off];
        __syncthreads();
    }
    if (threadIdx.x == 0) bsum[blockIdx.x] = s[0];
}

// phase 2: exclusive scan of 391 block sums (single small block)
__global__ void k_scan2(int* __restrict__ bsum) {
    __shared__ int s[512];
    int t = threadIdx.x;
    int v = (t < SCAN_NB) ? bsum[t] : 0;
    s[t] = v;
    __syncthreads();
    for (int off = 1; off < 512; off <<= 1) {
        int u = (t >= off) ? s[t - off] : 0;
        __syncthreads();
        s[t] += u;
        __syncthreads();
    }
    if (t < SCAN_NB) bsum[t] = s[t] - v;   // exclusive
}

// phase 3: local scan + offset; write rowstart/cursor/flag
__global__ void k_scan3(const int* __restrict__ cnt, const int* __restrict__ bsum,
                        int* __restrict__ rowstart, int* __restrict__ cursor,
                        float* __restrict__ flag) {
    __shared__ int s[SCAN_B];
    int i = blockIdx.x * SCAN_B + threadIdx.x;
    int v = (i < N_NODES) ? cnt[i] : 0;
    s[threadIdx.x] = v;
    __syncthreads();
    for (int off = 1; off < SCAN_B; off <<= 1) {
        int u = (threadIdx.x >= off) ? s[threadIdx.x - off] : 0;
        __syncthreads();
        s[threadIdx.x] += u;
        __syncthreads();
    }
    if (i < N_NODES) {
        int excl = s[threadIdx.x] - v + bsum[blockIdx.x];
        rowstart[i] = excl;
        cursor[i] = excl;
        flag[i] = (v > 0) ? 1.0f : 0.0f;
        if (i == N_NODES - 1) rowstart[N_NODES] = excl + v;
    }
}

__global__ void k_scatter(const int* __restrict__ ei, int* __restrict__ cursor,
                          int* __restrict__ eord, int* __restrict__ esrc) {
    int e = blockIdx.x * blockDim.x + threadIdx.x;
    if (e < N_EDGES) {
        int pos = atomicAdd(&cursor[ei[N_EDGES + e]], 1);
        eord[pos] = e;
        esrc[pos] = ei[e];
    }
}

// ---------------- composite edge weights: writes bf16-transposed WeT + fp32 bc ----------------
__global__ void k_prep(const float* __restrict__ edge_w, const float* __restrict__ edge_b,
                       const float* __restrict__ msg_w1, const float* __restrict__ msg_b1,
                       ushort* __restrict__ WeT, float* __restrict__ bc) {
    int j = threadIdx.x;
    int c = blockIdx.x;
    int l = blockIdx.y;
    const float* w1 = msg_w1 + (size_t)l * DD * DD;
    if (c < DE) {
        float s = 0.0f;
        for (int k = 0; k < DD; k++) s += edge_w[c*DD + k] * w1[k*DD + j];
        WeT[((size_t)l*DD + j)*DE + c] = f2bf(s);     // [l][j(out)][c(k)]
    } else {
        float s = msg_b1[l*DD + j];
        for (int k = 0; k < DD; k++) s += edge_b[k] * w1[k*DD + j];
        bc[l*DD + j] = s;
    }
}

// ---------------- batched transpose fp32 [R][C] -> bf16 [C][R] ----------------
struct TDesc { const float* src; ushort* dst; int R; int C; };
struct TPack { TDesc d[13]; };

__global__ void k_tball(TPack p) {
    TDesc t = p.d[blockIdx.y];
    int idx = blockIdx.x * 256 + threadIdx.x;
    if (idx < t.R * t.C) {
        int r = idx / t.C, c = idx % t.C;
        t.dst[(size_t)c * t.R + r] = f2bf(t.src[idx]);
    }
}

// ---------------- embed + fused nodeW1(l=0) ----------------
__global__ __launch_bounds__(256) void k_embed(
    const float* __restrict__ x, const ushort* __restrict__ WT,
    const float* __restrict__ bias, const ushort* __restrict__ W1T,
    float* __restrict__ node, ushort* __restrict__ slotA, int M)
{
    __shared__ ushort tr[4][16 * 136];
    int tid = threadIdx.x, lane = tid & 63, w = tid >> 6;
    int base = (blockIdx.x * 4 + w) * 16;
    bool act = base < M;
    int cq = lane & 15, quad = lane >> 4;
    ushort* trw = tr[w];
    f4v acc[8];
    if (act) {
        bf8v a[4];
        const float* Af = x + (size_t)(base + cq) * DD;
#pragma unroll
        for (int kc = 0; kc < 4; kc++) {
            float4 v0 = *(const float4*)(Af + kc * 32 + quad * 8);
            float4 v1 = *(const float4*)(Af + kc * 32 + quad * 8 + 4);
            bf8v t;
            t[0]=(short)f2bf(v0.x); t[1]=(short)f2bf(v0.y); t[2]=(short)f2bf(v0.z); t[3]=(short)f2bf(v0.w);
            t[4]=(short)f2bf(v1.x); t[5]=(short)f2bf(v1.y); t[6]=(short)f2bf(v1.z); t[7]=(short)f2bf(v1.w);
            a[kc] = t;
        }
#pragma unroll
        for (int ct = 0; ct < 8; ct++) acc[ct] = 0.0f;
#pragma unroll
        for (int ct = 0; ct < 8; ct++) {
            const ushort* Wr = WT + (size_t)(ct * 16 + cq) * DD;
#pragma unroll
            for (int kc = 0; kc < 4; kc++)
                acc[ct] = __builtin_amdgcn_mfma_f32_16x16x32_bf16(a[kc],
                    *(const bf8v*)(Wr + kc * 32 + quad * 8), acc[ct], 0, 0, 0);
        }
        int r0 = base + quad * 4;
#pragma unroll
        for (int ct = 0; ct < 8; ct++) {
            int col = ct * 16 + cq;
            float b_ = bias[col];
#pragma unroll
            for (int i = 0; i < 4; i++) {
                float v = acc[ct][i] + b_;
                node[(size_t)(r0 + i) * DD + col] = v;
                trw[(quad * 4 + i) * 136 + col] = f2bf(v);
            }
        }
    }
    __syncthreads();
    if (act) {
        bf8v a2[4];
#pragma unroll
        for (int kc = 0; kc < 4; kc++)
            a2[kc] = *(const bf8v*)(trw + cq * 136 + kc * 32 + quad * 8);
#pragma unroll
        for (int ct = 0; ct < 8; ct++) acc[ct] = 0.0f;
#pragma unroll
        for (int ct = 0; ct < 8; ct++) {
            const ushort* Wr = W1T + (size_t)(ct * 16 + cq) * DD;
#pragma unroll
            for (int kc = 0; kc < 4; kc++)
                acc[ct] = __builtin_amdgcn_mfma_f32_16x16x32_bf16(a2[kc],
                    *(const bf8v*)(Wr + kc * 32 + quad * 8), acc[ct], 0, 0, 0);
        }
        int r0 = base + quad * 4;
#pragma unroll
        for (int ct = 0; ct < 8; ct++) {
            int col = ct * 16 + cq;
#pragma unroll
            for (int i = 0; i < 4; i++)
                slotA[(size_t)(r0 + i) * DD + col] = f2bf(acc[ct][i]);
        }
    }
}

// ---------------- per-edge embedding MLP (MFMA, K=32), CSR order, node-range pass ----------------
__global__ __launch_bounds__(256) void k_emb1(
    const int* __restrict__ eord, const float* __restrict__ edge_attr,
    const ushort* __restrict__ WeT, const float* __restrict__ bcv,
    const int* __restrict__ rowstart, int n_lo, int n_hi, int cap,
    ushort* __restrict__ emb1h)
{
    __shared__ ushort tr[4][16 * 136];
    int tid = threadIdx.x, lane = tid & 63, w = tid >> 6;
    int tbase = (blockIdx.x * 4 + w) * 16;
    int cq = lane & 15, quad = lane >> 4;
    int j_lo = rowstart[n_lo], j_hi = rowstart[n_hi];
    int cnt = j_hi - j_lo; if (cnt > cap) cnt = cap;
    ushort* trw = tr[w];
    bool act = tbase < cnt;
    if (act) {
        int jl = tbase + cq;
        bf8v a;
#pragma unroll
        for (int t = 0; t < 8; t++) a[t] = 0;
        if (jl < cnt) {
            int e = eord[j_lo + jl];
            const float* ea = edge_attr + (size_t)e * DE + quad * 8;
            float4 v0 = *(const float4*)(ea);
            float4 v1 = *(const float4*)(ea + 4);
            a[0]=(short)f2bf(v0.x); a[1]=(short)f2bf(v0.y); a[2]=(short)f2bf(v0.z); a[3]=(short)f2bf(v0.w);
            a[4]=(short)f2bf(v1.x); a[5]=(short)f2bf(v1.y); a[6]=(short)f2bf(v1.z); a[7]=(short)f2bf(v1.w);
        }
#pragma unroll
        for (int ct = 0; ct < 8; ct++) {
            bf8v b = *(const bf8v*)(WeT + (size_t)(ct * 16 + cq) * DE + quad * 8);
            f4v z; z = 0.0f;
            f4v r = __builtin_amdgcn_mfma_f32_16x16x32_bf16(a, b, z, 0, 0, 0);
            int col = ct * 16 + cq;
            float b_ = bcv[col];
#pragma unroll
            for (int i = 0; i < 4; i++)
                trw[(quad * 4 + i) * 136 + col] = f2bf(r[i] + b_);
        }
    }
    __syncthreads();
    if (act) {
        int r = lane >> 2, ch = (lane & 3) * 32;
        int jl = tbase + r;
        if (jl < cnt) {
#pragma unroll
            for (int q = 0; q < 4; q++) {
                bf8v v = *(const bf8v*)(trw + r * 136 + ch + q * 8);
                *(bf8v*)(emb1h + (size_t)jl * DD + ch + q * 8) = v;
            }
        }
    }
}

// ---------------- lean edge aggregation: 1 wave/node, 2 cols/lane, uint loads ----------------
__global__ __launch_bounds__(256) void k_edge(
    const ushort* __restrict__ emb1h, const ushort* __restrict__ nodeW1,
    const int* __restrict__ esrc, const int* __restrict__ rowstart,
    int n_lo, int n_hi, int cap, ushort* __restrict__ aggh)
{
    int lane = threadIdx.x & 63;
    int w = threadIdx.x >> 6;
    int n = n_lo + blockIdx.x * 4 + w;
    if (n >= n_hi) return;
    int j_lo = rowstart[n_lo];
    int rs = rowstart[n], re0 = rowstart[n + 1];
    int lim = j_lo + cap;
    int re = (re0 > lim) ? lim : re0;
    float a0 = 0.0f, a1 = 0.0f;
    int j = rs;
    for (; j + 1 < re; j += 2) {
        int s0 = __builtin_amdgcn_readfirstlane(esrc[j]);
        int s1 = __builtin_amdgcn_readfirstlane(esrc[j + 1]);
        uint e0 = *(const uint*)(emb1h + (size_t)(j - j_lo) * DD + 2 * lane);
        uint e1 = *(const uint*)(emb1h + (size_t)(j + 1 - j_lo) * DD + 2 * lane);
        uint n0 = *(const uint*)(nodeW1 + (size_t)s0 * DD + 2 * lane);
        uint n1 = *(const uint*)(nodeW1 + (size_t)s1 * DD + 2 * lane);
        a0 += gelu_t(bf2f((ushort)(e0 & 0xffffu)) + bf2f((ushort)(n0 & 0xffffu)))
            + gelu_t(bf2f((ushort)(e1 & 0xffffu)) + bf2f((ushort)(n1 & 0xffffu)));
        a1 += gelu_t(bf2f((ushort)(e0 >> 16)) + bf2f((ushort)(n0 >> 16)))
            + gelu_t(bf2f((ushort)(e1 >> 16)) + bf2f((ushort)(n1 >> 16)));
    }
    if (j < re) {
        int s0 = __builtin_amdgcn_readfirstlane(esrc[j]);
        uint e0 = *(const uint*)(emb1h + (size_t)(j - j_lo) * DD + 2 * lane);
        uint n0 = *(const uint*)(nodeW1 + (size_t)s0 * DD + 2 * lane);
        a0 += gelu_t(bf2f((ushort)(e0 & 0xffffu)) + bf2f((ushort)(n0 & 0xffffu)));
        a1 += gelu_t(bf2f((ushort)(e0 >> 16)) + bf2f((ushort)(n0 >> 16)));
    }
    int deg = re0 - rs;
    float inv = (deg > 0) ? 1.0f / (float)deg : 0.0f;
    uint o = (uint)f2bf(a0 * inv) | ((uint)f2bf(a1 * inv) << 16);
    *(uint*)(aggh + (size_t)n * DD + 2 * lane) = o;
}

// ---------------- mega node MLP: B1 -> T -> u -> resid+LN -> (next nodeW1) ----------------
template<int FUSE>
__global__ __launch_bounds__(256) void k_mlp(
    const ushort* __restrict__ agg,
    const ushort* __restrict__ w2T, const float* __restrict__ b2,
    const float* __restrict__ flag,
    const ushort* __restrict__ u1T, const float* __restrict__ bu1,
    const ushort* __restrict__ u2T, const float* __restrict__ bu2,
    float* __restrict__ node,
    const float* __restrict__ lg, const float* __restrict__ lb,
    const ushort* __restrict__ w1nT, ushort* __restrict__ slotA, int M)
{
    __shared__ ushort tr[4][16 * 136];
    int tid = threadIdx.x, lane = tid & 63, w = tid >> 6;
    int base = (blockIdx.x * 4 + w) * 16;
    bool act = base < M;
    int cq = lane & 15, quad = lane >> 4;
    ushort* trw = tr[w];
    f4v acc[8];
    if (act) {
        bf8v a[4];
        const ushort* Ab = agg + (size_t)(base + cq) * DD;
#pragma unroll
        for (int kc = 0; kc < 4; kc++)
            a[kc] = *(const bf8v*)(Ab + kc * 32 + quad * 8);
#pragma unroll
        for (int ct = 0; ct < 8; ct++) acc[ct] = 0.0f;
#pragma unroll
        for (int ct = 0; ct < 8; ct++) {
            const ushort* Wr = w2T + (size_t)(ct * 16 + cq) * DD;
#pragma unroll
            for (int kc = 0; kc < 4; kc++)
                acc[ct] = __builtin_amdgcn_mfma_f32_16x16x32_bf16(a[kc],
                    *(const bf8v*)(Wr + kc * 32 + quad * 8), acc[ct], 0, 0, 0);
        }
        float fl[4];
#pragma unroll
        for (int i = 0; i < 4; i++) fl[i] = flag[base + quad * 4 + i];
#pragma unroll
        for (int ct = 0; ct < 8; ct++) {
            int col = ct * 16 + cq;
            float b_ = b2[col];
#pragma unroll
            for (int i = 0; i < 4; i++)
                trw[(quad * 4 + i) * 136 + col] = f2bf(acc[ct][i] + fl[i] * b_);
        }
    }
    __syncthreads();
    bf8v a2[4];
    if (act) {
#pragma unroll
        for (int kc = 0; kc < 4; kc++)
            a2[kc] = *(const bf8v*)(trw + cq * 136 + kc * 32 + quad * 8);
    }
    f4v accU[8];
#pragma unroll
    for (int ct = 0; ct < 8; ct++) accU[ct] = 0.0f;
#pragma unroll
    for (int h = 0; h < 2; h++) {
        __syncthreads();
        if (act) {
#pragma unroll
            for (int ct = 0; ct < 8; ct++) acc[ct] = 0.0f;
#pragma unroll
            for (int ct = 0; ct < 8; ct++) {
                const ushort* Wr = u1T + (size_t)(h * 128 + ct * 16 + cq) * DD;
#pragma unroll
                for (int kc = 0; kc < 4; kc++)
                    acc[ct] = __builtin_amdgcn_mfma_f32_16x16x32_bf16(a2[kc],
                        *(const bf8v*)(Wr + kc * 32 + quad * 8), acc[ct], 0, 0, 0);
            }
#pragma unroll
            for (int ct = 0; ct < 8; ct++) {
                int col = ct * 16 + cq;
                float b_ = bu1[h * 128 + col];
#pragma unroll
                for (int i = 0; i < 4; i++)
                    trw[(quad * 4 + i) * 136 + col] = f2bf(gelu_f(acc[ct][i] + b_));
            }
        }
        __syncthreads();
        if (act) {
            bf8v tf[4];
#pragma unroll
            for (int kc = 0; kc < 4; kc++)
                tf[kc] = *(const bf8v*)(trw + cq * 136 + kc * 32 + quad * 8);
#pragma unroll
            for (int ct = 0; ct < 8; ct++) {
                const ushort* Wr = u2T + (size_t)(ct * 16 + cq) * 256 + h * 128;
#pragma unroll
                for (int kc = 0; kc < 4; kc++)
                    accU[ct] = __builtin_amdgcn_mfma_f32_16x16x32_bf16(tf[kc],
                        *(const bf8v*)(Wr + kc * 32 + quad * 8), accU[ct], 0, 0, 0);
            }
        }
    }
    if (act) {
        int r0 = base + quad * 4;
        float xv[8][4], lgc[8], lbc[8];
#pragma unroll
        for (int ct = 0; ct < 8; ct++) {
            int col = ct * 16 + cq;
            float b_ = bu2[col];
            lgc[ct] = lg[col]; lbc[ct] = lb[col];
#pragma unroll
            for (int i = 0; i < 4; i++)
                xv[ct][i] = accU[ct][i] + b_ + node[(size_t)(r0 + i) * DD + col];
        }
#pragma unroll
        for (int i = 0; i < 4; i++) {
            float s = 0.0f;
#pragma unroll
            for (int ct = 0; ct < 8; ct++) s += xv[ct][i];
            s += __shfl_xor(s, 1); s += __shfl_xor(s, 2);
            s += __shfl_xor(s, 4); s += __shfl_xor(s, 8);
            float m = s * (1.0f / 128.0f);
            float vv = 0.0f;
#pragma unroll
            for (int ct = 0; ct < 8; ct++) { float d = xv[ct][i] - m; vv += d * d; }
            vv += __shfl_xor(vv, 1); vv += __shfl_xor(vv, 2);
            vv += __shfl_xor(vv, 4); vv += __shfl_xor(vv, 8);
            float inv = rsqrtf(vv * (1.0f / 128.0f) + 1e-5f);
#pragma unroll
            for (int ct = 0; ct < 8; ct++) {
                int col = ct * 16 + cq;
                float y = (xv[ct][i] - m) * inv * lgc[ct] + lbc[ct];
                node[(size_t)(r0 + i) * DD + col] = y;
                if (FUSE) trw[(quad * 4 + i) * 136 + col] = f2bf(y);
            }
        }
    }
    if (FUSE) {
        __syncthreads();
        if (act) {
            bf8v nf[4];
#pragma unroll
            for (int kc = 0; kc < 4; kc++)
                nf[kc] = *(const bf8v*)(trw + cq * 136 + kc * 32 + quad * 8);
#pragma unroll
            for (int ct = 0; ct < 8; ct++) acc[ct] = 0.0f;
#pragma unroll
            for (int ct = 0; ct < 8; ct++) {
                const ushort* Wr = w1nT + (size_t)(ct * 16 + cq) * DD;
#pragma unroll
                for (int kc = 0; kc < 4; kc++)
                    acc[ct] = __builtin_amdgcn_mfma_f32_16x16x32_bf16(nf[kc],
                        *(const bf8v*)(Wr + kc * 32 + quad * 8), acc[ct], 0, 0, 0);
            }
            int r0 = base + quad * 4;
#pragma unroll
            for (int ct = 0; ct < 8; ct++) {
                int col = ct * 16 + cq;
#pragma unroll
                for (int i = 0; i < 4; i++)
                    slotA[(size_t)(r0 + i) * DD + col] = f2bf(acc[ct][i]);
            }
        }
    }
}

// ---------------- pooling: 128 chunks/segment for latency hiding ----------------
__global__ void k_pool_partial(const float* __restrict__ node, float* __restrict__ partial) {
    int seg = blockIdx.x, chunk = blockIdx.y, j = threadIdx.x;
    int segbase = seg * 14286;
    int segcnt = (seg == 6) ? 14284 : 14286;
    const int per = 112;                       // ceil(14286/128)
    int lo = chunk * per, hi = min(lo + per, segcnt);
    float s = 0.0f;
    for (int r = lo; r < hi; r++) s += node[(size_t)(segbase + r) * DD + j];
    partial[(size_t)(seg * 128 + chunk) * DD + j] = s;
}

__global__ void k_pool_final(const float* __restrict__ partial, const float* __restrict__ g,
                             const float* __restrict__ b, float* __restrict__ out) {
    __shared__ float red[128];
    int j = threadIdx.x;
    float tok[8];
    float tot = 0.0f;
#pragma unroll
    for (int s = 0; s < 7; s++) {
        float v = 0.0f;
        for (int c = 0; c < 128; c++) v += partial[(size_t)(s * 128 + c) * DD + j];
        tok[1 + s] = v / ((s == 6) ? 14284.0f : 14286.0f);
        tot += v;
    }
    tok[0] = tot / 100000.0f;
    for (int t = 0; t < 8; t++) {
        float x = tok[t];
        red[j] = x; __syncthreads();
        for (int off = 64; off > 0; off >>= 1) {
            if (j < off) red[j] += red[j + off];
            __syncthreads();
        }
        float m = red[0] / 128.0f;
        __syncthreads();
        float d = x - m;
        red[j] = d * d; __syncthreads();
        for (int off = 64; off > 0; off >>= 1) {
            if (j < off) red[j] += red[j + off];
            __syncthreads();
        }
        float var = red[0] / 128.0f;
        __syncthreads();
        out[t * DD + j] = d * rsqrtf(var + 1e-5f) * g[j] + b[j];
    }
}

extern "C" void kernel_launch(void* const* d_in, const int* in_sizes, int n_in,
                              void* d_out, int out_size, void* d_ws, size_t ws_size,
                              hipStream_t stream) {
    const float* x         = (const float*)d_in[0];
    const int*   ei        = (const int*)d_in[1];
    const float* edge_attr = (const float*)d_in[2];
    const float* node_w    = (const float*)d_in[3];
    const float* node_b    = (const float*)d_in[4];
    const float* edge_w    = (const float*)d_in[5];
    const float* edge_b    = (const float*)d_in[6];
    const float* msg_w1    = (const float*)d_in[7];
    const float* msg_b1    = (const float*)d_in[8];
    const float* msg_w2    = (const float*)d_in[9];
    const float* msg_b2    = (const float*)d_in[10];
    const float* upd_w1    = (const float*)d_in[11];
    const float* upd_b1    = (const float*)d_in[12];
    const float* upd_w2    = (const float*)d_in[13];
    const float* upd_b2    = (const float*)d_in[14];
    const float* ln_g      = (const float*)d_in[15];
    const float* ln_b      = (const float*)d_in[16];
    const float* out_g     = (const float*)d_in[17];
    const float* out_b     = (const float*)d_in[18];
    float* out = (float*)d_out;

    // ---- workspace layout (emb1h takes the remainder) ----
    char* pw = (char*)d_ws;
    auto alloc = [&](size_t bytes) -> void* {
        void* r = (void*)pw;
        pw += (bytes + 255) & ~(size_t)255;
        return r;
    };
    float*  node_f  = (float*) alloc((size_t)N_NODES * DD * 4);
    ushort* slotA   = (ushort*)alloc((size_t)N_NODES * DD * 2);
    ushort* aggb    = (ushort*)alloc((size_t)N_NODES * DD * 2);
    float*  bc      = (float*) alloc((size_t)3 * DD * 4);
    ushort* WeT     = (ushort*)alloc((size_t)3 * DD * DE * 2);
    float*  partial = (float*) alloc((size_t)7 * 128 * DD * 4);
    float*  degflag = (float*) alloc((size_t)N_NODES * 4);
    ushort* node_wT = (ushort*)alloc((size_t)DD * DD * 2);
    ushort* msg_w1T = (ushort*)alloc((size_t)3 * DD * DD * 2);
    ushort* msg_w2T = (ushort*)alloc((size_t)3 * DD * DD * 2);
    ushort* upd_w1T = (ushort*)alloc((size_t)3 * 256 * DD * 2);
    ushort* upd_w2T = (ushort*)alloc((size_t)3 * DD * 256 * 2);
    int* cnt        = (int*)   alloc((size_t)N_NODES * 4);
    int* rowstart   = (int*)   alloc((size_t)(N_NODES + 1) * 4);
    int* cursor     = (int*)   alloc((size_t)N_NODES * 4);
    int* bsum       = (int*)   alloc((size_t)512 * 4);
    int* eord       = (int*)   alloc((size_t)N_EDGES * 4);
    int* esrc       = (int*)   alloc((size_t)N_EDGES * 4);
    ushort* emb1h   = (ushort*)pw;
    size_t avail = (ws_size > (size_t)(pw - (char*)d_ws)) ? ws_size - (size_t)(pw - (char*)d_ws) : 0;

    // prefer P=2 (chunk ~82 MB stays L3-resident between k_emb1 write and k_edge read)
    int P; size_t capE;
    if      (avail >= (size_t)(N_EDGES/2 + 60000) * DD * 2)     { P = 2; capE = N_EDGES/2 + 60000; }
    else if (avail >= (size_t)(N_EDGES/4 + 40000) * DD * 2)     { P = 4; capE = N_EDGES/4 + 40000; }
    else                                                        { P = 8; capE = avail / (DD * 2); }

    hipMemsetAsync(cnt, 0, N_NODES * sizeof(int), stream);
    k_count  <<<(N_EDGES + 255) / 256, 256, 0, stream>>>(ei, cnt);
    k_scan1  <<<SCAN_NB, SCAN_B, 0, stream>>>(cnt, bsum);
    k_scan2  <<<1, 512, 0, stream>>>(bsum);
    k_scan3  <<<SCAN_NB, SCAN_B, 0, stream>>>(cnt, bsum, rowstart, cursor, degflag);
    k_scatter<<<(N_EDGES + 255) / 256, 256, 0, stream>>>(ei, cursor, eord, esrc);
    k_prep   <<<dim3(DE + 1, 3), DD, 0, stream>>>(edge_w, edge_b, msg_w1, msg_b1, WeT, bc);

    // batched weight transposes -> bf16 [out][in]
    TPack tp;
    tp.d[0] = { node_w, node_wT, DD, DD };
    for (int l = 0; l < 3; l++) {
        tp.d[1 + l*4 + 0] = { msg_w1 + (size_t)l*DD*DD,  msg_w1T + (size_t)l*DD*DD,  DD, DD };
        tp.d[1 + l*4 + 1] = { msg_w2 + (size_t)l*DD*DD,  msg_w2T + (size_t)l*DD*DD,  DD, DD };
        tp.d[1 + l*4 + 2] = { upd_w1 + (size_t)l*DD*256, upd_w1T + (size_t)l*256*DD, DD, 256 };
        tp.d[1 + l*4 + 3] = { upd_w2 + (size_t)l*256*DD, upd_w2T + (size_t)l*DD*256, 256, DD };
    }
    k_tball<<<dim3(128, 13), 256, 0, stream>>>(tp);

    const int GB = (N_NODES / 16 + 3) / 4;  // 1563
    k_embed<<<GB, 256, 0, stream>>>(x, node_wT, node_b, msg_w1T, node_f, slotA, N_NODES);

    for (int l = 0; l < 3; l++) {
        for (int pI = 0; pI < P; pI++) {
            int n_lo = (int)((long long)N_NODES * pI / P);
            int n_hi = (int)((long long)N_NODES * (pI + 1) / P);
            int gb1 = (int)((capE + 63) / 64);
            k_emb1<<<gb1, 256, 0, stream>>>(eord, edge_attr, WeT + (size_t)l*DD*DE,
                bc + (size_t)l*DD, rowstart, n_lo, n_hi, (int)capE, emb1h);
            k_edge<<<(n_hi - n_lo + 3) / 4, 256, 0, stream>>>(emb1h, slotA, esrc, rowstart,
                n_lo, n_hi, (int)capE, aggb);
        }
        if (l < 2) {
            k_mlp<1><<<GB, 256, 0, stream>>>(aggb,
                msg_w2T + (size_t)l*DD*DD, msg_b2 + (size_t)l*DD, degflag,
                upd_w1T + (size_t)l*256*DD, upd_b1 + (size_t)l*256,
                upd_w2T + (size_t)l*DD*256, upd_b2 + (size_t)l*DD,
                node_f, ln_g + (size_t)l*DD, ln_b + (size_t)l*DD,
                msg_w1T + (size_t)(l+1)*DD*DD, slotA, N_NODES);
        } else {
            k_mlp<0><<<GB, 256, 0, stream>>>(aggb,
                msg_w2T + (size_t)l*DD*DD, msg_b2 + (size_t)l*DD, degflag,
                upd_w1T + (size_t)l*256*DD, upd_b1 + (size_t)l*256,
                upd_w2T + (size_t)l*DD*256, upd_b2 + (size_t)l*DD,
                node_f, ln_g + (size_t)l*DD, ln_b + (size_t)l*DD,
                msg_w1T, slotA, N_NODES);
        }
    }

    k_pool_partial<<<dim3(7, 128), DD, 0, stream>>>(node_f, partial);
    k_pool_final  <<<1, DD, 0, stream>>>(partial, out_g, out_b, out);
}